// Round 3
// baseline (475.966 us; speedup 1.0000x reference)
//
#include <hip/hip_runtime.h>
#include <cstdint>
#include <cstddef>

#define D 128
#define BN_EPS 1e-5f
#define NEG_INF -3.0e38f

typedef __attribute__((ext_vector_type(8))) short bf16x8;
typedef __attribute__((ext_vector_type(4))) float f32x4;

// ---------- helpers ----------
static __device__ __forceinline__ unsigned short f2bf(float f) {
    uint32_t u = __float_as_uint(f);
    uint32_t r = (u + 0x7fffu + ((u >> 16) & 1u)) >> 16;
    return (unsigned short)r;
}

// sum across each 16-lane row via DPP adds (no LDS/DS ops):
// xor1 (quad_perm 1,0,3,2) ; xor2 (quad_perm 2,3,0,1) ; row_ror:4 ; row_ror:8
static __device__ __forceinline__ float hsum16(float x) {
    x += __int_as_float(__builtin_amdgcn_update_dpp(0, __float_as_int(x), 0xB1, 0xF, 0xF, true));
    x += __int_as_float(__builtin_amdgcn_update_dpp(0, __float_as_int(x), 0x4E, 0xF, 0xF, true));
    x += __int_as_float(__builtin_amdgcn_update_dpp(0, __float_as_int(x), 0x124, 0xF, 0xF, true));
    x += __int_as_float(__builtin_amdgcn_update_dpp(0, __float_as_int(x), 0x128, 0xF, 0xF, true));
    return x;
}

// ---------- zero ----------
__global__ void zero_kernel(int* cnt, int n, int* esrc_tail) {
    int i = blockIdx.x * 256 + threadIdx.x;
    if (i < n) cnt[i] = 0;
    if (i < 8) esrc_tail[i] = 0;
}

// ---------- CSR build ----------
__global__ void hist_kernel(const int* __restrict__ dst, int* __restrict__ cnt, int E) {
    int e = blockIdx.x * 256 + threadIdx.x;
    if (e < E) atomicAdd(&cnt[dst[e]], 1);
}

__global__ void scan_block(const int* __restrict__ cnt, int* __restrict__ row_start,
                           int* __restrict__ bsum, int n) {
    __shared__ int tmp[256];
    int tid = threadIdx.x;
    int i = blockIdx.x * 256 + tid;
    int v = (i < n) ? cnt[i] : 0;
    tmp[tid] = v; __syncthreads();
    for (int off = 1; off < 256; off <<= 1) {
        int t = (tid >= off) ? tmp[tid - off] : 0;
        __syncthreads();
        tmp[tid] += t; __syncthreads();
    }
    if (i < n) row_start[i + 1] = tmp[tid];
    if (tid == 255) bsum[blockIdx.x] = tmp[255];
}

__global__ void scan_bsum(int* bsum, int nb) {
    __shared__ int tmp[256];
    int tid = threadIdx.x;
    int v = (tid < nb) ? bsum[tid] : 0;
    tmp[tid] = v; __syncthreads();
    for (int off = 1; off < 256; off <<= 1) {
        int t = (tid >= off) ? tmp[tid - off] : 0;
        __syncthreads();
        tmp[tid] += t; __syncthreads();
    }
    if (tid < nb) bsum[tid] = tmp[tid];
}

__global__ void scan_fix(int* __restrict__ row_start, const int* __restrict__ bsum,
                         int* __restrict__ cursor, int n) {
    int i = blockIdx.x * 256 + threadIdx.x;
    if (i < n) {
        int add = (blockIdx.x > 0) ? bsum[blockIdx.x - 1] : 0;
        int val = row_start[i + 1] + add;
        row_start[i + 1] = val;
        if (i + 1 < n) cursor[i + 1] = val;
    }
    if (i == 0) { row_start[0] = 0; cursor[0] = 0; }
}

__global__ void scatter_kernel(const int* __restrict__ src, const int* __restrict__ dst,
                               int* __restrict__ cursor, int* __restrict__ esrc, int E) {
    int e = blockIdx.x * 256 + threadIdx.x;
    if (e < E) {
        int p = atomicAdd(&cursor[dst[e]], 1);
        esrc[p] = src[e];
    }
}

// ---------- weight repack into MFMA B-fragment order ----------
__global__ void repack_w(const float* __restrict__ Wl, const float* __restrict__ Wr,
                         unsigned short* __restrict__ Bp) {
    int idx = blockIdx.x * 256 + threadIdx.x;   // 0..32767
    int i    = idx & 7;
    int lane = (idx >> 3) & 63;
    int kt   = (idx >> 9) & 3;
    int jt   = idx >> 11;                        // 0..15
    int k   = kt * 32 + (lane >> 4) * 8 + i;
    int col = jt * 16 + (lane & 15);
    float v = (col < 128) ? Wl[k * 128 + col] : Wr[k * 128 + (col - 128)];
    Bp[idx] = f2bf(v);
}

// ---------- MFMA dual GEMM: [n x 128] @ [128 x 256] -> xl (bf16), xr (f32) ----------
// One wave computes 32 rows x 256 cols (2 A-frag halves share each B-frag load).
template<bool BN>
__global__ __launch_bounds__(256, 1) void gemm_mfma(
    const float* __restrict__ X, const unsigned short* __restrict__ Bp,
    const float* __restrict__ scale, const float* __restrict__ shift,
    unsigned short* __restrict__ xl, float* __restrict__ xr, int n)
{
    int wid = threadIdx.x >> 6, lane = threadIdx.x & 63;
    int nw = (n + 31) >> 5;
    int wrow = blockIdx.x * 4 + wid;
    if (wrow >= nw) return;
    int r0 = wrow * 32;
    int m = lane & 15, hi = lane >> 4;

    f32x4 accA[16], accB[16];
    #pragma unroll
    for (int jt = 0; jt < 16; ++jt) {
        accA[jt] = (f32x4){0.f, 0.f, 0.f, 0.f};
        accB[jt] = (f32x4){0.f, 0.f, 0.f, 0.f};
    }

    int rA = r0 + m;      if (rA > n - 1) rA = n - 1;
    int rB = r0 + 16 + m; if (rB > n - 1) rB = n - 1;
    const float* xrowA = X + (size_t)rA * D;
    const float* xrowB = X + (size_t)rB * D;

    #pragma unroll
    for (int kt = 0; kt < 4; ++kt) {
        int kb = kt * 32 + hi * 8;
        float sca[8], shf[8];
        if (BN) {
            float4 s0 = *(const float4*)(scale + kb);
            float4 s1 = *(const float4*)(scale + kb + 4);
            float4 h0 = *(const float4*)(shift + kb);
            float4 h1 = *(const float4*)(shift + kb + 4);
            sca[0]=s0.x; sca[1]=s0.y; sca[2]=s0.z; sca[3]=s0.w;
            sca[4]=s1.x; sca[5]=s1.y; sca[6]=s1.z; sca[7]=s1.w;
            shf[0]=h0.x; shf[1]=h0.y; shf[2]=h0.z; shf[3]=h0.w;
            shf[4]=h1.x; shf[5]=h1.y; shf[6]=h1.z; shf[7]=h1.w;
        }
        float4 a0 = *(const float4*)(xrowA + kb);
        float4 a1 = *(const float4*)(xrowA + kb + 4);
        float4 b0 = *(const float4*)(xrowB + kb);
        float4 b1 = *(const float4*)(xrowB + kb + 4);
        float avA[8] = {a0.x, a0.y, a0.z, a0.w, a1.x, a1.y, a1.z, a1.w};
        float avB[8] = {b0.x, b0.y, b0.z, b0.w, b1.x, b1.y, b1.z, b1.w};
        bf16x8 afragA, afragB;
        #pragma unroll
        for (int i = 0; i < 8; ++i) {
            float va = avA[i], vb = avB[i];
            if (BN) {
                va = fmaxf(va * sca[i] + shf[i], 0.f);
                vb = fmaxf(vb * sca[i] + shf[i], 0.f);
            }
            afragA[i] = (short)f2bf(va);
            afragB[i] = (short)f2bf(vb);
        }
        #pragma unroll
        for (int jt = 0; jt < 16; ++jt) {
            bf16x8 bfrag = *(const bf16x8*)(Bp + (size_t)((jt * 4 + kt) * 64 + lane) * 8);
            accA[jt] = __builtin_amdgcn_mfma_f32_16x16x32_bf16(afragA, bfrag, accA[jt], 0, 0, 0);
            accB[jt] = __builtin_amdgcn_mfma_f32_16x16x32_bf16(afragB, bfrag, accB[jt], 0, 0, 0);
        }
    }

    // C/D layout: col = lane&15, row = (lane>>4)*4 + reg
    #pragma unroll
    for (int jt = 0; jt < 16; ++jt) {
        int col = jt * 16 + m;
        #pragma unroll
        for (int r = 0; r < 4; ++r) {
            int rowA = r0 + hi * 4 + r;
            int rowB = rowA + 16;
            if (rowA < n) {
                float v = accA[jt][r];
                if (jt < 8) xl[(size_t)rowA * D + col] = f2bf(v);
                else        xr[(size_t)rowA * D + (col - 128)] = v;
            }
            if (rowB < n) {
                float v = accB[jt][r];
                if (jt < 8) xl[(size_t)rowB * D + col] = f2bf(v);
                else        xr[(size_t)rowB * D + (col - 128)] = v;
            }
        }
    }
}

// ---------- node-centric GATv2: DPP reduce, 8-edge batches, batched defer-max, exp2 ----------
__global__ __launch_bounds__(256) void gat_kernel(
    const unsigned short* __restrict__ xl, const float* __restrict__ xr,
    const float* __restrict__ att, const float* __restrict__ bias,
    const int* __restrict__ row_start, const int* __restrict__ esrc,
    float* __restrict__ h, int n)
{
    const float L2E = 1.44269504089f;    // fold log2(e) into att: softmax invariant
    int wid = threadIdx.x >> 6;
    int lane = threadIdx.x & 63;
    int v = blockIdx.x * 4 + wid;
    if (v >= n) return;

    int c0 = lane * 2;
    float a0 = att[c0] * L2E, a1 = att[c0 + 1] * L2E;
    float xr0 = xr[(size_t)v * D + c0];
    float xr1 = xr[(size_t)v * D + c0 + 1];

    // self-loop initializes running max
    uint32_t ws = *(const uint32_t*)(xl + (size_t)v * D + c0);
    float sx0 = __uint_as_float(ws << 16);
    float sx1 = __uint_as_float(ws & 0xffff0000u);
    float t0 = sx0 + xr0; t0 = fmaxf(t0, 0.2f * t0);
    float t1 = sx1 + xr1; t1 = fmaxf(t1, 0.2f * t1);
    float m = hsum16(fmaf(a0, t0, a1 * t1));
    float den = 1.f;
    float acc0 = sx0, acc1 = sx1, acc0b = 0.f, acc1b = 0.f;

    int p = row_start[v], pe = row_start[v + 1];
    for (int i = p; i < pe; i += 8) {
        int rem = pe - i;                        // wave-uniform
        uint32_t w[8]; float lg[8], x0v[8], x1v[8];
        #pragma unroll
        for (int j = 0; j < 8; ++j) {
            int u = esrc[i + j];                 // padded+zeroed tail: always safe
            w[j] = *(const uint32_t*)(xl + (size_t)u * D + c0);
        }
        #pragma unroll
        for (int j = 0; j < 8; ++j) {
            float x0 = __uint_as_float(w[j] << 16);
            float x1 = __uint_as_float(w[j] & 0xffff0000u);
            x0v[j] = x0; x1v[j] = x1;
            float f0 = x0 + xr0; f0 = fmaxf(f0, 0.2f * f0);
            float f1 = x1 + xr1; f1 = fmaxf(f1, 0.2f * f1);
            lg[j] = hsum16(fmaf(a0, f0, a1 * f1));
        }
        #pragma unroll
        for (int j = 0; j < 8; ++j) if (j >= rem) lg[j] = NEG_INF;
        float mx = fmaxf(fmaxf(fmaxf(lg[0], lg[1]), fmaxf(lg[2], lg[3])),
                         fmaxf(fmaxf(lg[4], lg[5]), fmaxf(lg[6], lg[7])));
        if (__any(mx > m + 8.f)) {               // rare: rescale once per batch
            float nm = fmaxf(m, mx);
            float sc = exp2f(m - nm);
            den *= sc; acc0 *= sc; acc1 *= sc; acc0b *= sc; acc1b *= sc;
            m = nm;
        }
        float pex[8];
        #pragma unroll
        for (int j = 0; j < 8; ++j) pex[j] = exp2f(lg[j] - m);   // tail -> 0
        den += ((pex[0] + pex[1]) + (pex[2] + pex[3])) + ((pex[4] + pex[5]) + (pex[6] + pex[7]));
        #pragma unroll
        for (int j = 0; j < 8; j += 2) {
            acc0  = fmaf(pex[j],     x0v[j],     acc0);
            acc1  = fmaf(pex[j],     x1v[j],     acc1);
            acc0b = fmaf(pex[j + 1], x0v[j + 1], acc0b);
            acc1b = fmaf(pex[j + 1], x1v[j + 1], acc1b);
        }
    }
    float inv = 1.0f / den;
    h[(size_t)v * D + c0]     = (acc0 + acc0b) * inv + bias[c0];
    h[(size_t)v * D + c0 + 1] = (acc1 + acc1b) * inv + bias[c0 + 1];
}

// ---------- BN stats (atomic-free two-stage) ----------
__global__ __launch_bounds__(256) void bn_stats(const float* __restrict__ h,
                                                float* __restrict__ psum, float* __restrict__ psum2, int n)
{
    int ch = threadIdx.x & 127;
    int half = threadIdx.x >> 7;
    float s = 0.f, s2 = 0.f;
    for (int r = blockIdx.x * 2 + half; r < n; r += gridDim.x * 2) {
        float v = h[(size_t)r * D + ch];
        s += v; s2 += v * v;
    }
    __shared__ float sm[256];
    sm[threadIdx.x] = s; __syncthreads();
    if (half == 0) psum[blockIdx.x * 128 + ch] = s + sm[threadIdx.x + 128];
    __syncthreads();
    sm[threadIdx.x] = s2; __syncthreads();
    if (half == 0) psum2[blockIdx.x * 128 + ch] = s2 + sm[threadIdx.x + 128];
}

__global__ void bn_final(const float* __restrict__ psum, const float* __restrict__ psum2,
                         const float* __restrict__ gamma, const float* __restrict__ beta,
                         float* __restrict__ scale, float* __restrict__ shift,
                         float inv_n, int nblk)
{
    int c = threadIdx.x;     // 128 threads
    float s = 0.f, s2 = 0.f;
    for (int b = 0; b < nblk; ++b) {
        s  += psum[b * 128 + c];
        s2 += psum2[b * 128 + c];
    }
    float mu = s * inv_n;
    float var = s2 * inv_n - mu * mu;
    float inv = rsqrtf(var + BN_EPS);
    float sc = gamma[c] * inv;
    scale[c] = sc;
    shift[c] = beta[c] - mu * sc;
}

// ---------- final: out = relu(bn2(h2) + x) ----------
__global__ __launch_bounds__(256) void final_kernel(
    const float* __restrict__ h2, const float* __restrict__ x,
    const float* __restrict__ scale, const float* __restrict__ shift,
    float* __restrict__ out, int total)
{
    int i = blockIdx.x * 256 + threadIdx.x;
    if (i * 4 >= total) return;
    float4 hv = ((const float4*)h2)[i];
    float4 xv = ((const float4*)x)[i];
    int c = (i * 4) & 127;
    float4 o;
    o.x = fmaxf(hv.x * scale[c + 0] + shift[c + 0] + xv.x, 0.f);
    o.y = fmaxf(hv.y * scale[c + 1] + shift[c + 1] + xv.y, 0.f);
    o.z = fmaxf(hv.z * scale[c + 2] + shift[c + 2] + xv.z, 0.f);
    o.w = fmaxf(hv.w * scale[c + 3] + shift[c + 3] + xv.w, 0.f);
    ((float4*)out)[i] = o;
}

// ---------- launch ----------
extern "C" void kernel_launch(void* const* d_in, const int* in_sizes, int n_in,
                              void* d_out, int out_size, void* d_ws, size_t ws_size,
                              hipStream_t stream)
{
    const float* x    = (const float*)d_in[0];
    const int*   ei   = (const int*)  d_in[1];
    const float* Wl1  = (const float*)d_in[2];
    const float* Wr1  = (const float*)d_in[3];
    const float* att1 = (const float*)d_in[4];
    const float* b1   = (const float*)d_in[5];
    const float* g1   = (const float*)d_in[6];
    const float* be1  = (const float*)d_in[7];
    const float* Wl2  = (const float*)d_in[8];
    const float* Wr2  = (const float*)d_in[9];
    const float* att2 = (const float*)d_in[10];
    const float* b2   = (const float*)d_in[11];
    const float* g2   = (const float*)d_in[12];
    const float* be2  = (const float*)d_in[13];
    float* out = (float*)d_out;

    int n = in_sizes[0] / D;
    int E = in_sizes[1] / 2;
    const int* e_src = ei;
    const int* e_dst = ei + E;

    char* w = (char*)d_ws;
    auto alloc = [&](size_t bytes) -> char* {
        char* p = w;
        w += (bytes + 255) / 256 * 256;
        return p;
    };
    unsigned short* xl = (unsigned short*)alloc((size_t)n * D * 2);
    float* xr          = (float*)alloc((size_t)n * D * 4);
    float* h           = (float*)alloc((size_t)n * D * 4);
    int* row_start     = (int*)alloc((size_t)(n + 1) * 4);
    int* cnt           = (int*)alloc((size_t)n * 4);
    int* cursor        = (int*)alloc((size_t)n * 4);
    int* esrc          = (int*)alloc((size_t)(E + 8) * 4);
    int* bsum          = (int*)alloc(256 * 4);
    float* bn          = (float*)alloc(4 * 128 * 4);      // scale1, shift1, scale2, shift2
    float* psum        = (float*)alloc(256 * 128 * 4);
    float* psum2       = (float*)alloc(256 * 128 * 4);
    unsigned short* Bp1 = (unsigned short*)alloc(32768 * 2);
    unsigned short* Bp2 = (unsigned short*)alloc(32768 * 2);

    int nb = (n + 255) / 256;
    int gemm_blocks = (((n + 31) / 32) + 3) / 4;

    zero_kernel<<<(n + 255) / 256, 256, 0, stream>>>(cnt, n, esrc + E);
    hist_kernel<<<(E + 255) / 256, 256, 0, stream>>>(e_dst, cnt, E);
    scan_block<<<nb, 256, 0, stream>>>(cnt, row_start, bsum, n);
    scan_bsum<<<1, 256, 0, stream>>>(bsum, nb);
    scan_fix<<<nb, 256, 0, stream>>>(row_start, bsum, cursor, n);
    scatter_kernel<<<(E + 255) / 256, 256, 0, stream>>>(e_src, e_dst, cursor, esrc, E);
    repack_w<<<128, 256, 0, stream>>>(Wl1, Wr1, Bp1);
    repack_w<<<128, 256, 0, stream>>>(Wl2, Wr2, Bp2);

    // layer 1
    gemm_mfma<false><<<gemm_blocks, 256, 0, stream>>>(x, Bp1, nullptr, nullptr, xl, xr, n);
    gat_kernel<<<(n + 3) / 4, 256, 0, stream>>>(xl, xr, att1, b1, row_start, esrc, h, n);
    bn_stats<<<256, 256, 0, stream>>>(h, psum, psum2, n);
    bn_final<<<1, 128, 0, stream>>>(psum, psum2, g1, be1, bn + 0, bn + 128, 1.0f / n, 256);

    // layer 2 (BN1+ReLU fused into GEMM A-load)
    gemm_mfma<true><<<gemm_blocks, 256, 0, stream>>>(h, Bp2, bn + 0, bn + 128, xl, xr, n);
    gat_kernel<<<(n + 3) / 4, 256, 0, stream>>>(xl, xr, att2, b2, row_start, esrc, h, n);
    bn_stats<<<256, 256, 0, stream>>>(h, psum, psum2, n);
    bn_final<<<1, 128, 0, stream>>>(psum, psum2, g2, be2, bn + 256, bn + 384, 1.0f / n, 256);

    final_kernel<<<((n * D / 4) + 255) / 256, 256, 0, stream>>>(h, x, bn + 256, bn + 384, out, n * D);
}

// Round 4
// 474.057 us; speedup vs baseline: 1.0040x; 1.0040x over previous
//
#include <hip/hip_runtime.h>
#include <cstdint>
#include <cstddef>

#define D 128
#define BN_EPS 1e-5f
#define NEG_INF -3.0e38f

typedef __attribute__((ext_vector_type(8))) short bf16x8;
typedef __attribute__((ext_vector_type(4))) float f32x4;

// ---------- helpers ----------
static __device__ __forceinline__ unsigned short f2bf(float f) {
    uint32_t u = __float_as_uint(f);
    uint32_t r = (u + 0x7fffu + ((u >> 16) & 1u)) >> 16;
    return (unsigned short)r;
}

// sum across each 16-lane row via DPP adds (no LDS/DS ops)
static __device__ __forceinline__ float hsum16(float x) {
    x += __int_as_float(__builtin_amdgcn_update_dpp(0, __float_as_int(x), 0xB1, 0xF, 0xF, true));
    x += __int_as_float(__builtin_amdgcn_update_dpp(0, __float_as_int(x), 0x4E, 0xF, 0xF, true));
    x += __int_as_float(__builtin_amdgcn_update_dpp(0, __float_as_int(x), 0x124, 0xF, 0xF, true));
    x += __int_as_float(__builtin_amdgcn_update_dpp(0, __float_as_int(x), 0x128, 0xF, 0xF, true));
    return x;
}

// ---------- zero ----------
__global__ void zero_kernel(int* cnt, int n, int* esrc_tail) {
    int i = blockIdx.x * 256 + threadIdx.x;
    if (i < n) cnt[i] = 0;
    if (i < 8) esrc_tail[i] = 0;
}

// ---------- CSR build ----------
__global__ void hist_kernel(const int* __restrict__ dst, int* __restrict__ cnt, int E) {
    int e = blockIdx.x * 256 + threadIdx.x;
    if (e < E) atomicAdd(&cnt[dst[e]], 1);
}

__global__ void scan_block(const int* __restrict__ cnt, int* __restrict__ row_start,
                           int* __restrict__ bsum, int n) {
    __shared__ int tmp[256];
    int tid = threadIdx.x;
    int i = blockIdx.x * 256 + tid;
    int v = (i < n) ? cnt[i] : 0;
    tmp[tid] = v; __syncthreads();
    for (int off = 1; off < 256; off <<= 1) {
        int t = (tid >= off) ? tmp[tid - off] : 0;
        __syncthreads();
        tmp[tid] += t; __syncthreads();
    }
    if (i < n) row_start[i + 1] = tmp[tid];
    if (tid == 255) bsum[blockIdx.x] = tmp[255];
}

__global__ void scan_bsum(int* bsum, int nb) {
    __shared__ int tmp[256];
    int tid = threadIdx.x;
    int v = (tid < nb) ? bsum[tid] : 0;
    tmp[tid] = v; __syncthreads();
    for (int off = 1; off < 256; off <<= 1) {
        int t = (tid >= off) ? tmp[tid - off] : 0;
        __syncthreads();
        tmp[tid] += t; __syncthreads();
    }
    if (tid < nb) bsum[tid] = tmp[tid];
}

__global__ void scan_fix(int* __restrict__ row_start, const int* __restrict__ bsum,
                         int* __restrict__ cursor, int n) {
    int i = blockIdx.x * 256 + threadIdx.x;
    if (i < n) {
        int add = (blockIdx.x > 0) ? bsum[blockIdx.x - 1] : 0;
        int val = row_start[i + 1] + add;
        row_start[i + 1] = val;
        if (i + 1 < n) cursor[i + 1] = val;
    }
    if (i == 0) { row_start[0] = 0; cursor[0] = 0; }
}

__global__ void scatter_kernel(const int* __restrict__ src, const int* __restrict__ dst,
                               int* __restrict__ cursor, int* __restrict__ esrc, int E) {
    int e = blockIdx.x * 256 + threadIdx.x;
    if (e < E) {
        int p = atomicAdd(&cursor[dst[e]], 1);
        esrc[p] = src[e];
    }
}

// ---------- weight repack into MFMA B-fragment order ----------
__global__ void repack_w(const float* __restrict__ Wl, const float* __restrict__ Wr,
                         unsigned short* __restrict__ Bp) {
    int idx = blockIdx.x * 256 + threadIdx.x;   // 0..32767
    int i    = idx & 7;
    int lane = (idx >> 3) & 63;
    int kt   = (idx >> 9) & 3;
    int jt   = idx >> 11;                        // 0..15
    int k   = kt * 32 + (lane >> 4) * 8 + i;
    int col = jt * 16 + (lane & 15);
    float v = (col < 128) ? Wl[k * 128 + col] : Wr[k * 128 + (col - 128)];
    Bp[idx] = f2bf(v);
}

// ---------- MFMA dual GEMM: [n x 128] @ [128 x 256] -> xl (bf16), xr (f32) ----------
// B (64KB, fragment-ordered) staged in LDS once per block, shared by 4 waves.
// One wave computes 32 rows x 256 cols (2 A-frag halves share each B-frag read).
template<bool BN>
__global__ __launch_bounds__(256, 2) void gemm_mfma(
    const float* __restrict__ X, const unsigned short* __restrict__ Bp,
    const float* __restrict__ scale, const float* __restrict__ shift,
    unsigned short* __restrict__ xl, float* __restrict__ xr, int n)
{
    __shared__ unsigned short smem[32768];      // 64KB: full fragment-ordered B
    {
        const float4* s = (const float4*)Bp;
        float4* d = (float4*)smem;
        #pragma unroll
        for (int it = 0; it < 16; ++it)
            d[it * 256 + threadIdx.x] = s[it * 256 + threadIdx.x];
    }
    __syncthreads();

    int wid = threadIdx.x >> 6, lane = threadIdx.x & 63;
    int nw = (n + 31) >> 5;
    int wrow = blockIdx.x * 4 + wid;
    if (wrow >= nw) return;                     // after barrier: safe
    int r0 = wrow * 32;
    int m = lane & 15, hi = lane >> 4;

    f32x4 accA[16], accB[16];
    #pragma unroll
    for (int jt = 0; jt < 16; ++jt) {
        accA[jt] = (f32x4){0.f, 0.f, 0.f, 0.f};
        accB[jt] = (f32x4){0.f, 0.f, 0.f, 0.f};
    }

    int rA = r0 + m;      if (rA > n - 1) rA = n - 1;
    int rB = r0 + 16 + m; if (rB > n - 1) rB = n - 1;
    const float* xrowA = X + (size_t)rA * D;
    const float* xrowB = X + (size_t)rB * D;

    #pragma unroll
    for (int kt = 0; kt < 4; ++kt) {
        int kb = kt * 32 + hi * 8;
        float sca[8], shf[8];
        if (BN) {
            float4 s0 = *(const float4*)(scale + kb);
            float4 s1 = *(const float4*)(scale + kb + 4);
            float4 h0 = *(const float4*)(shift + kb);
            float4 h1 = *(const float4*)(shift + kb + 4);
            sca[0]=s0.x; sca[1]=s0.y; sca[2]=s0.z; sca[3]=s0.w;
            sca[4]=s1.x; sca[5]=s1.y; sca[6]=s1.z; sca[7]=s1.w;
            shf[0]=h0.x; shf[1]=h0.y; shf[2]=h0.z; shf[3]=h0.w;
            shf[4]=h1.x; shf[5]=h1.y; shf[6]=h1.z; shf[7]=h1.w;
        }
        float4 a0 = *(const float4*)(xrowA + kb);
        float4 a1 = *(const float4*)(xrowA + kb + 4);
        float4 b0 = *(const float4*)(xrowB + kb);
        float4 b1 = *(const float4*)(xrowB + kb + 4);
        float avA[8] = {a0.x, a0.y, a0.z, a0.w, a1.x, a1.y, a1.z, a1.w};
        float avB[8] = {b0.x, b0.y, b0.z, b0.w, b1.x, b1.y, b1.z, b1.w};
        bf16x8 afragA, afragB;
        #pragma unroll
        for (int i = 0; i < 8; ++i) {
            float va = avA[i], vb = avB[i];
            if (BN) {
                va = fmaxf(va * sca[i] + shf[i], 0.f);
                vb = fmaxf(vb * sca[i] + shf[i], 0.f);
            }
            afragA[i] = (short)f2bf(va);
            afragB[i] = (short)f2bf(vb);
        }
        #pragma unroll
        for (int jt = 0; jt < 16; ++jt) {
            bf16x8 bfrag = *(const bf16x8*)(smem + (size_t)((jt * 4 + kt) * 64 + lane) * 8);
            accA[jt] = __builtin_amdgcn_mfma_f32_16x16x32_bf16(afragA, bfrag, accA[jt], 0, 0, 0);
            accB[jt] = __builtin_amdgcn_mfma_f32_16x16x32_bf16(afragB, bfrag, accB[jt], 0, 0, 0);
        }
    }

    // C/D layout: col = lane&15, row = (lane>>4)*4 + reg
    #pragma unroll
    for (int jt = 0; jt < 16; ++jt) {
        int col = jt * 16 + m;
        #pragma unroll
        for (int r = 0; r < 4; ++r) {
            int rowA = r0 + hi * 4 + r;
            int rowB = rowA + 16;
            if (rowA < n) {
                float v = accA[jt][r];
                if (jt < 8) xl[(size_t)rowA * D + col] = f2bf(v);
                else        xr[(size_t)rowA * D + (col - 128)] = v;
            }
            if (rowB < n) {
                float v = accB[jt][r];
                if (jt < 8) xl[(size_t)rowB * D + col] = f2bf(v);
                else        xr[(size_t)rowB * D + (col - 128)] = v;
            }
        }
    }
}

// ---------- node-centric GATv2: DPP reduce, 8-edge batches, batched defer-max, exp2 ----------
__global__ __launch_bounds__(256) void gat_kernel(
    const unsigned short* __restrict__ xl, const float* __restrict__ xr,
    const float* __restrict__ att, const float* __restrict__ bias,
    const int* __restrict__ row_start, const int* __restrict__ esrc,
    float* __restrict__ h, int n)
{
    const float L2E = 1.44269504089f;    // fold log2(e) into att: softmax invariant
    int wid = threadIdx.x >> 6;
    int lane = threadIdx.x & 63;
    int v = blockIdx.x * 4 + wid;
    if (v >= n) return;

    int c0 = lane * 2;
    const uint32_t* xl32 = (const uint32_t*)xl;   // 32-bit row offsets: u<<6 dwords
    float a0 = att[c0] * L2E, a1 = att[c0 + 1] * L2E;
    float xr0 = xr[(size_t)v * D + c0];
    float xr1 = xr[(size_t)v * D + c0 + 1];

    // self-loop initializes running max
    uint32_t ws = xl32[((uint32_t)v << 6) + (uint32_t)lane];
    float sx0 = __uint_as_float(ws << 16);
    float sx1 = __uint_as_float(ws & 0xffff0000u);
    float t0 = sx0 + xr0; t0 = fmaxf(t0, 0.2f * t0);
    float t1 = sx1 + xr1; t1 = fmaxf(t1, 0.2f * t1);
    float m = hsum16(fmaf(a0, t0, a1 * t1));
    float den = 1.f;
    float acc0 = sx0, acc1 = sx1, acc0b = 0.f, acc1b = 0.f;

    int p = row_start[v], pe = row_start[v + 1];
    for (int i = p; i < pe; i += 8) {
        int rem = pe - i;                        // wave-uniform
        uint32_t w[8]; float lg[8], x0v[8], x1v[8];
        #pragma unroll
        for (int j = 0; j < 8; ++j) {
            uint32_t u = (uint32_t)esrc[i + j];  // padded+zeroed tail: always safe
            w[j] = xl32[(u << 6) + (uint32_t)lane];
        }
        #pragma unroll
        for (int j = 0; j < 8; ++j) {
            float x0 = __uint_as_float(w[j] << 16);
            float x1 = __uint_as_float(w[j] & 0xffff0000u);
            x0v[j] = x0; x1v[j] = x1;
            float f0 = x0 + xr0; f0 = fmaxf(f0, 0.2f * f0);
            float f1 = x1 + xr1; f1 = fmaxf(f1, 0.2f * f1);
            lg[j] = hsum16(fmaf(a0, f0, a1 * f1));
        }
        #pragma unroll
        for (int j = 0; j < 8; ++j) if (j >= rem) lg[j] = NEG_INF;
        float mx = fmaxf(fmaxf(fmaxf(lg[0], lg[1]), fmaxf(lg[2], lg[3])),
                         fmaxf(fmaxf(lg[4], lg[5]), fmaxf(lg[6], lg[7])));
        if (__any(mx > m + 8.f)) {               // rare: rescale once per batch
            float nm = fmaxf(m, mx);
            float sc = exp2f(m - nm);
            den *= sc; acc0 *= sc; acc1 *= sc; acc0b *= sc; acc1b *= sc;
            m = nm;
        }
        float pex[8];
        #pragma unroll
        for (int j = 0; j < 8; ++j) pex[j] = exp2f(lg[j] - m);   // tail -> 0
        den += ((pex[0] + pex[1]) + (pex[2] + pex[3])) + ((pex[4] + pex[5]) + (pex[6] + pex[7]));
        #pragma unroll
        for (int j = 0; j < 8; j += 2) {
            acc0  = fmaf(pex[j],     x0v[j],     acc0);
            acc1  = fmaf(pex[j],     x1v[j],     acc1);
            acc0b = fmaf(pex[j + 1], x0v[j + 1], acc0b);
            acc1b = fmaf(pex[j + 1], x1v[j + 1], acc1b);
        }
    }
    float inv = 1.0f / den;
    h[(size_t)v * D + c0]     = (acc0 + acc0b) * inv + bias[c0];
    h[(size_t)v * D + c0 + 1] = (acc1 + acc1b) * inv + bias[c0 + 1];
}

// ---------- BN stats (atomic-free two-stage, 64 partials) ----------
__global__ __launch_bounds__(256) void bn_stats(const float* __restrict__ h,
                                                float* __restrict__ psum, float* __restrict__ psum2, int n)
{
    int ch = threadIdx.x & 127;
    int half = threadIdx.x >> 7;
    float s = 0.f, s2 = 0.f;
    for (int r = blockIdx.x * 2 + half; r < n; r += gridDim.x * 2) {
        float v = h[(size_t)r * D + ch];
        s += v; s2 += v * v;
    }
    __shared__ float sm[256];
    sm[threadIdx.x] = s; __syncthreads();
    if (half == 0) psum[blockIdx.x * 128 + ch] = s + sm[threadIdx.x + 128];
    __syncthreads();
    sm[threadIdx.x] = s2; __syncthreads();
    if (half == 0) psum2[blockIdx.x * 128 + ch] = s2 + sm[threadIdx.x + 128];
}

__global__ void bn_final(const float* __restrict__ psum, const float* __restrict__ psum2,
                         const float* __restrict__ gamma, const float* __restrict__ beta,
                         float* __restrict__ scale, float* __restrict__ shift,
                         float inv_n, int nblk)
{
    int c = threadIdx.x & 127;                  // 256 threads, 2-way split over partials
    int half = threadIdx.x >> 7;
    float s = 0.f, s2 = 0.f;
    for (int b = half; b < nblk; b += 2) {
        s  += psum[b * 128 + c];
        s2 += psum2[b * 128 + c];
    }
    __shared__ float sm[256], sm2[256];
    sm[threadIdx.x] = s; sm2[threadIdx.x] = s2; __syncthreads();
    if (half == 0) {
        s  += sm[threadIdx.x + 128];
        s2 += sm2[threadIdx.x + 128];
        float mu = s * inv_n;
        float var = s2 * inv_n - mu * mu;
        float inv = rsqrtf(var + BN_EPS);
        float sc = gamma[c] * inv;
        scale[c] = sc;
        shift[c] = beta[c] - mu * sc;
    }
}

// ---------- final: out = relu(bn2(h2) + x) ----------
__global__ __launch_bounds__(256) void final_kernel(
    const float* __restrict__ h2, const float* __restrict__ x,
    const float* __restrict__ scale, const float* __restrict__ shift,
    float* __restrict__ out, int total)
{
    int i = blockIdx.x * 256 + threadIdx.x;
    if (i * 4 >= total) return;
    float4 hv = ((const float4*)h2)[i];
    float4 xv = ((const float4*)x)[i];
    int c = (i * 4) & 127;
    float4 o;
    o.x = fmaxf(hv.x * scale[c + 0] + shift[c + 0] + xv.x, 0.f);
    o.y = fmaxf(hv.y * scale[c + 1] + shift[c + 1] + xv.y, 0.f);
    o.z = fmaxf(hv.z * scale[c + 2] + shift[c + 2] + xv.z, 0.f);
    o.w = fmaxf(hv.w * scale[c + 3] + shift[c + 3] + xv.w, 0.f);
    ((float4*)out)[i] = o;
}

// ---------- launch ----------
extern "C" void kernel_launch(void* const* d_in, const int* in_sizes, int n_in,
                              void* d_out, int out_size, void* d_ws, size_t ws_size,
                              hipStream_t stream)
{
    const float* x    = (const float*)d_in[0];
    const int*   ei   = (const int*)  d_in[1];
    const float* Wl1  = (const float*)d_in[2];
    const float* Wr1  = (const float*)d_in[3];
    const float* att1 = (const float*)d_in[4];
    const float* b1   = (const float*)d_in[5];
    const float* g1   = (const float*)d_in[6];
    const float* be1  = (const float*)d_in[7];
    const float* Wl2  = (const float*)d_in[8];
    const float* Wr2  = (const float*)d_in[9];
    const float* att2 = (const float*)d_in[10];
    const float* b2   = (const float*)d_in[11];
    const float* g2   = (const float*)d_in[12];
    const float* be2  = (const float*)d_in[13];
    float* out = (float*)d_out;

    int n = in_sizes[0] / D;
    int E = in_sizes[1] / 2;
    const int* e_src = ei;
    const int* e_dst = ei + E;

    char* w = (char*)d_ws;
    auto alloc = [&](size_t bytes) -> char* {
        char* p = w;
        w += (bytes + 255) / 256 * 256;
        return p;
    };
    unsigned short* xl = (unsigned short*)alloc((size_t)n * D * 2);
    float* xr          = (float*)alloc((size_t)n * D * 4);
    float* h           = (float*)alloc((size_t)n * D * 4);
    int* row_start     = (int*)alloc((size_t)(n + 1) * 4);
    int* cnt           = (int*)alloc((size_t)n * 4);
    int* cursor        = (int*)alloc((size_t)n * 4);
    int* esrc          = (int*)alloc((size_t)(E + 8) * 4);
    int* bsum          = (int*)alloc(256 * 4);
    float* bn          = (float*)alloc(4 * 128 * 4);      // scale1, shift1, scale2, shift2
    float* psum        = (float*)alloc(64 * 128 * 4);
    float* psum2       = (float*)alloc(64 * 128 * 4);
    unsigned short* Bp1 = (unsigned short*)alloc(32768 * 2);
    unsigned short* Bp2 = (unsigned short*)alloc(32768 * 2);

    int nb = (n + 255) / 256;
    int gemm_blocks = (((n + 31) / 32) + 3) / 4;

    zero_kernel<<<(n + 255) / 256, 256, 0, stream>>>(cnt, n, esrc + E);
    hist_kernel<<<(E + 255) / 256, 256, 0, stream>>>(e_dst, cnt, E);
    scan_block<<<nb, 256, 0, stream>>>(cnt, row_start, bsum, n);
    scan_bsum<<<1, 256, 0, stream>>>(bsum, nb);
    scan_fix<<<nb, 256, 0, stream>>>(row_start, bsum, cursor, n);
    scatter_kernel<<<(E + 255) / 256, 256, 0, stream>>>(e_src, e_dst, cursor, esrc, E);
    repack_w<<<128, 256, 0, stream>>>(Wl1, Wr1, Bp1);
    repack_w<<<128, 256, 0, stream>>>(Wl2, Wr2, Bp2);

    // layer 1
    gemm_mfma<false><<<gemm_blocks, 256, 0, stream>>>(x, Bp1, nullptr, nullptr, xl, xr, n);
    gat_kernel<<<(n + 3) / 4, 256, 0, stream>>>(xl, xr, att1, b1, row_start, esrc, h, n);
    bn_stats<<<64, 256, 0, stream>>>(h, psum, psum2, n);
    bn_final<<<1, 256, 0, stream>>>(psum, psum2, g1, be1, bn + 0, bn + 128, 1.0f / n, 64);

    // layer 2 (BN1+ReLU fused into GEMM A-load)
    gemm_mfma<true><<<gemm_blocks, 256, 0, stream>>>(h, Bp2, bn + 0, bn + 128, xl, xr, n);
    gat_kernel<<<(n + 3) / 4, 256, 0, stream>>>(xl, xr, att2, b2, row_start, esrc, h, n);
    bn_stats<<<64, 256, 0, stream>>>(h, psum, psum2, n);
    bn_final<<<1, 256, 0, stream>>>(psum, psum2, g2, be2, bn + 256, bn + 384, 1.0f / n, 64);

    final_kernel<<<((n * D / 4) + 255) / 256, 256, 0, stream>>>(h, x, bn + 256, bn + 384, out, n * D);
}

// Round 5
// 401.015 us; speedup vs baseline: 1.1869x; 1.1821x over previous
//
#include <hip/hip_runtime.h>
#include <cstdint>
#include <cstddef>

#define D 128
#define BN_EPS 1e-5f
#define NEG_INF -3.0e38f
#define BN_BLOCKS 512

typedef __attribute__((ext_vector_type(8))) short bf16x8;
typedef __attribute__((ext_vector_type(4))) float f32x4;

// ---------- helpers ----------
static __device__ __forceinline__ unsigned short f2bf(float f) {
    uint32_t u = __float_as_uint(f);
    uint32_t r = (u + 0x7fffu + ((u >> 16) & 1u)) >> 16;
    return (unsigned short)r;
}

// sum across each 16-lane row via DPP adds (no LDS/DS ops)
static __device__ __forceinline__ float hsum16(float x) {
    x += __int_as_float(__builtin_amdgcn_update_dpp(0, __float_as_int(x), 0xB1, 0xF, 0xF, true));
    x += __int_as_float(__builtin_amdgcn_update_dpp(0, __float_as_int(x), 0x4E, 0xF, 0xF, true));
    x += __int_as_float(__builtin_amdgcn_update_dpp(0, __float_as_int(x), 0x124, 0xF, 0xF, true));
    x += __int_as_float(__builtin_amdgcn_update_dpp(0, __float_as_int(x), 0x128, 0xF, 0xF, true));
    return x;
}

// ---------- zero ----------
__global__ void zero_kernel(int* cnt, int n, int* esrc_tail) {
    int i = blockIdx.x * 256 + threadIdx.x;
    if (i < n) cnt[i] = 0;
    if (i < 8) esrc_tail[i] = 0;
}

// ---------- CSR build ----------
__global__ void hist_kernel(const int* __restrict__ dst, int* __restrict__ cnt, int E) {
    int e = blockIdx.x * 256 + threadIdx.x;
    if (e < E) atomicAdd(&cnt[dst[e]], 1);
}

__global__ void scan_block(const int* __restrict__ cnt, int* __restrict__ row_start,
                           int* __restrict__ bsum, int n) {
    __shared__ int tmp[256];
    int tid = threadIdx.x;
    int i = blockIdx.x * 256 + tid;
    int v = (i < n) ? cnt[i] : 0;
    tmp[tid] = v; __syncthreads();
    for (int off = 1; off < 256; off <<= 1) {
        int t = (tid >= off) ? tmp[tid - off] : 0;
        __syncthreads();
        tmp[tid] += t; __syncthreads();
    }
    if (i < n) row_start[i + 1] = tmp[tid];
    if (tid == 255) bsum[blockIdx.x] = tmp[255];
}

__global__ void scan_bsum(int* bsum, int nb) {
    __shared__ int tmp[256];
    int tid = threadIdx.x;
    int v = (tid < nb) ? bsum[tid] : 0;
    tmp[tid] = v; __syncthreads();
    for (int off = 1; off < 256; off <<= 1) {
        int t = (tid >= off) ? tmp[tid - off] : 0;
        __syncthreads();
        tmp[tid] += t; __syncthreads();
    }
    if (tid < nb) bsum[tid] = tmp[tid];
}

__global__ void scan_fix(int* __restrict__ row_start, const int* __restrict__ bsum,
                         int* __restrict__ cursor, int n) {
    int i = blockIdx.x * 256 + threadIdx.x;
    if (i < n) {
        int add = (blockIdx.x > 0) ? bsum[blockIdx.x - 1] : 0;
        int val = row_start[i + 1] + add;
        row_start[i + 1] = val;
        if (i + 1 < n) cursor[i + 1] = val;
    }
    if (i == 0) { row_start[0] = 0; cursor[0] = 0; }
}

__global__ void scatter_kernel(const int* __restrict__ src, const int* __restrict__ dst,
                               int* __restrict__ cursor, int* __restrict__ esrc, int E) {
    int e = blockIdx.x * 256 + threadIdx.x;
    if (e < E) {
        int p = atomicAdd(&cursor[dst[e]], 1);
        esrc[p] = src[e];
    }
}

// ---------- weight repack into MFMA B-fragment order ----------
__global__ void repack_w(const float* __restrict__ Wl, const float* __restrict__ Wr,
                         unsigned short* __restrict__ Bp) {
    int idx = blockIdx.x * 256 + threadIdx.x;   // 0..32767
    int i    = idx & 7;
    int lane = (idx >> 3) & 63;
    int kt   = (idx >> 9) & 3;
    int jt   = idx >> 11;                        // 0..15
    int k   = kt * 32 + (lane >> 4) * 8 + i;
    int col = jt * 16 + (lane & 15);
    float v = (col < 128) ? Wl[k * 128 + col] : Wr[k * 128 + (col - 128)];
    Bp[idx] = f2bf(v);
}

// ---------- MFMA dual GEMM: [n x 128] @ [128 x 256] -> xl (bf16), xr (f32) ----------
// B (64KB, fragment-ordered) staged in LDS once per block, shared by 4 waves.
// One wave computes 32 rows x 256 cols (2 A-frag halves share each B-frag read).
template<bool BN>
__global__ __launch_bounds__(256, 2) void gemm_mfma(
    const float* __restrict__ X, const unsigned short* __restrict__ Bp,
    const float* __restrict__ scale, const float* __restrict__ shift,
    unsigned short* __restrict__ xl, float* __restrict__ xr, int n)
{
    __shared__ unsigned short smem[32768];      // 64KB: full fragment-ordered B
    {
        const float4* s = (const float4*)Bp;
        float4* d = (float4*)smem;
        #pragma unroll
        for (int it = 0; it < 16; ++it)
            d[it * 256 + threadIdx.x] = s[it * 256 + threadIdx.x];
    }
    __syncthreads();

    int wid = threadIdx.x >> 6, lane = threadIdx.x & 63;
    int nw = (n + 31) >> 5;
    int wrow = blockIdx.x * 4 + wid;
    if (wrow >= nw) return;                     // after barrier: safe
    int r0 = wrow * 32;
    int m = lane & 15, hi = lane >> 4;

    f32x4 accA[16], accB[16];
    #pragma unroll
    for (int jt = 0; jt < 16; ++jt) {
        accA[jt] = (f32x4){0.f, 0.f, 0.f, 0.f};
        accB[jt] = (f32x4){0.f, 0.f, 0.f, 0.f};
    }

    int rA = r0 + m;      if (rA > n - 1) rA = n - 1;
    int rB = r0 + 16 + m; if (rB > n - 1) rB = n - 1;
    const float* xrowA = X + (size_t)rA * D;
    const float* xrowB = X + (size_t)rB * D;

    #pragma unroll
    for (int kt = 0; kt < 4; ++kt) {
        int kb = kt * 32 + hi * 8;
        float sca[8], shf[8];
        if (BN) {
            float4 s0 = *(const float4*)(scale + kb);
            float4 s1 = *(const float4*)(scale + kb + 4);
            float4 h0 = *(const float4*)(shift + kb);
            float4 h1 = *(const float4*)(shift + kb + 4);
            sca[0]=s0.x; sca[1]=s0.y; sca[2]=s0.z; sca[3]=s0.w;
            sca[4]=s1.x; sca[5]=s1.y; sca[6]=s1.z; sca[7]=s1.w;
            shf[0]=h0.x; shf[1]=h0.y; shf[2]=h0.z; shf[3]=h0.w;
            shf[4]=h1.x; shf[5]=h1.y; shf[6]=h1.z; shf[7]=h1.w;
        }
        float4 a0 = *(const float4*)(xrowA + kb);
        float4 a1 = *(const float4*)(xrowA + kb + 4);
        float4 b0 = *(const float4*)(xrowB + kb);
        float4 b1 = *(const float4*)(xrowB + kb + 4);
        float avA[8] = {a0.x, a0.y, a0.z, a0.w, a1.x, a1.y, a1.z, a1.w};
        float avB[8] = {b0.x, b0.y, b0.z, b0.w, b1.x, b1.y, b1.z, b1.w};
        bf16x8 afragA, afragB;
        #pragma unroll
        for (int i = 0; i < 8; ++i) {
            float va = avA[i], vb = avB[i];
            if (BN) {
                va = fmaxf(va * sca[i] + shf[i], 0.f);
                vb = fmaxf(vb * sca[i] + shf[i], 0.f);
            }
            afragA[i] = (short)f2bf(va);
            afragB[i] = (short)f2bf(vb);
        }
        #pragma unroll
        for (int jt = 0; jt < 16; ++jt) {
            bf16x8 bfrag = *(const bf16x8*)(smem + (size_t)((jt * 4 + kt) * 64 + lane) * 8);
            accA[jt] = __builtin_amdgcn_mfma_f32_16x16x32_bf16(afragA, bfrag, accA[jt], 0, 0, 0);
            accB[jt] = __builtin_amdgcn_mfma_f32_16x16x32_bf16(afragB, bfrag, accB[jt], 0, 0, 0);
        }
    }

    // C/D layout: col = lane&15, row = (lane>>4)*4 + reg
    #pragma unroll
    for (int jt = 0; jt < 16; ++jt) {
        int col = jt * 16 + m;
        #pragma unroll
        for (int r = 0; r < 4; ++r) {
            int rowA = r0 + hi * 4 + r;
            int rowB = rowA + 16;
            if (rowA < n) {
                float v = accA[jt][r];
                if (jt < 8) xl[(size_t)rowA * D + col] = f2bf(v);
                else        xr[(size_t)rowA * D + (col - 128)] = v;
            }
            if (rowB < n) {
                float v = accB[jt][r];
                if (jt < 8) xl[(size_t)rowB * D + col] = f2bf(v);
                else        xr[(size_t)rowB * D + (col - 128)] = v;
            }
        }
    }
}

// ---------- node-centric GATv2: DPP reduce, 8-edge batches, batched defer-max, exp2 ----------
__global__ __launch_bounds__(256) void gat_kernel(
    const unsigned short* __restrict__ xl, const float* __restrict__ xr,
    const float* __restrict__ att, const float* __restrict__ bias,
    const int* __restrict__ row_start, const int* __restrict__ esrc,
    float* __restrict__ h, int n)
{
    const float L2E = 1.44269504089f;    // fold log2(e) into att: softmax invariant
    int wid = threadIdx.x >> 6;
    int lane = threadIdx.x & 63;
    int v = blockIdx.x * 4 + wid;
    if (v >= n) return;

    int c0 = lane * 2;
    const uint32_t* xl32 = (const uint32_t*)xl;   // 32-bit row offsets: u<<6 dwords
    float a0 = att[c0] * L2E, a1 = att[c0 + 1] * L2E;
    float xr0 = xr[(size_t)v * D + c0];
    float xr1 = xr[(size_t)v * D + c0 + 1];

    // self-loop initializes running max
    uint32_t ws = xl32[((uint32_t)v << 6) + (uint32_t)lane];
    float sx0 = __uint_as_float(ws << 16);
    float sx1 = __uint_as_float(ws & 0xffff0000u);
    float t0 = sx0 + xr0; t0 = fmaxf(t0, 0.2f * t0);
    float t1 = sx1 + xr1; t1 = fmaxf(t1, 0.2f * t1);
    float m = hsum16(fmaf(a0, t0, a1 * t1));
    float den = 1.f;
    float acc0 = sx0, acc1 = sx1, acc0b = 0.f, acc1b = 0.f;

    int p = row_start[v], pe = row_start[v + 1];
    for (int i = p; i < pe; i += 8) {
        int rem = pe - i;                        // wave-uniform
        uint32_t w[8]; float lg[8], x0v[8], x1v[8];
        #pragma unroll
        for (int j = 0; j < 8; ++j) {
            uint32_t u = (uint32_t)esrc[i + j];  // padded+zeroed tail: always safe
            w[j] = xl32[(u << 6) + (uint32_t)lane];
        }
        #pragma unroll
        for (int j = 0; j < 8; ++j) {
            float x0 = __uint_as_float(w[j] << 16);
            float x1 = __uint_as_float(w[j] & 0xffff0000u);
            x0v[j] = x0; x1v[j] = x1;
            float f0 = x0 + xr0; f0 = fmaxf(f0, 0.2f * f0);
            float f1 = x1 + xr1; f1 = fmaxf(f1, 0.2f * f1);
            lg[j] = hsum16(fmaf(a0, f0, a1 * f1));
        }
        #pragma unroll
        for (int j = 0; j < 8; ++j) if (j >= rem) lg[j] = NEG_INF;
        float mx = fmaxf(fmaxf(fmaxf(lg[0], lg[1]), fmaxf(lg[2], lg[3])),
                         fmaxf(fmaxf(lg[4], lg[5]), fmaxf(lg[6], lg[7])));
        if (__any(mx > m + 8.f)) {               // rare: rescale once per batch
            float nm = fmaxf(m, mx);
            float sc = exp2f(m - nm);
            den *= sc; acc0 *= sc; acc1 *= sc; acc0b *= sc; acc1b *= sc;
            m = nm;
        }
        float pex[8];
        #pragma unroll
        for (int j = 0; j < 8; ++j) pex[j] = exp2f(lg[j] - m);   // tail -> 0
        den += ((pex[0] + pex[1]) + (pex[2] + pex[3])) + ((pex[4] + pex[5]) + (pex[6] + pex[7]));
        #pragma unroll
        for (int j = 0; j < 8; j += 2) {
            acc0  = fmaf(pex[j],     x0v[j],     acc0);
            acc1  = fmaf(pex[j],     x1v[j],     acc1);
            acc0b = fmaf(pex[j + 1], x0v[j + 1], acc0b);
            acc1b = fmaf(pex[j + 1], x1v[j + 1], acc1b);
        }
    }
    float inv = 1.0f / den;
    h[(size_t)v * D + c0]     = (acc0 + acc0b) * inv + bias[c0];
    h[(size_t)v * D + c0 + 1] = (acc1 + acc1b) * inv + bias[c0 + 1];
}

// ---------- BN stats: BW-shaped. 8 rows/block/iter as float4, LDS tree reduce ----------
__global__ __launch_bounds__(256) void bn_stats(const float* __restrict__ h,
                                                float* __restrict__ psum, float* __restrict__ psum2, int n)
{
    int c4 = threadIdx.x & 31;   // float4 slot within a row (channels c4*4..c4*4+3)
    int ty = threadIdx.x >> 5;   // row slot 0..7
    float sx = 0.f, sy = 0.f, sz = 0.f, sw = 0.f;
    float qx = 0.f, qy = 0.f, qz = 0.f, qw = 0.f;
    for (int r = blockIdx.x * 8 + ty; r < n; r += gridDim.x * 8) {
        float4 v = *(const float4*)(h + (size_t)r * D + c4 * 4);
        sx += v.x; sy += v.y; sz += v.z; sw += v.w;
        qx = fmaf(v.x, v.x, qx); qy = fmaf(v.y, v.y, qy);
        qz = fmaf(v.z, v.z, qz); qw = fmaf(v.w, v.w, qw);
    }
    __shared__ float4 smA[256], smB[256];
    smA[threadIdx.x] = make_float4(sx, sy, sz, sw);
    smB[threadIdx.x] = make_float4(qx, qy, qz, qw);
    __syncthreads();
    #pragma unroll
    for (int off = 128; off >= 32; off >>= 1) {
        if (threadIdx.x < off) {
            float4 a = smA[threadIdx.x], b = smA[threadIdx.x + off];
            smA[threadIdx.x] = make_float4(a.x + b.x, a.y + b.y, a.z + b.z, a.w + b.w);
            float4 c = smB[threadIdx.x], d2 = smB[threadIdx.x + off];
            smB[threadIdx.x] = make_float4(c.x + d2.x, c.y + d2.y, c.z + d2.z, c.w + d2.w);
        }
        __syncthreads();
    }
    if (threadIdx.x < 32) {
        ((float4*)psum)[blockIdx.x * 32 + threadIdx.x]  = smA[threadIdx.x];
        ((float4*)psum2)[blockIdx.x * 32 + threadIdx.x] = smB[threadIdx.x];
    }
}

__global__ void bn_final(const float* __restrict__ psum, const float* __restrict__ psum2,
                         const float* __restrict__ gamma, const float* __restrict__ beta,
                         float* __restrict__ scale, float* __restrict__ shift,
                         float inv_n, int nblk)
{
    int c = threadIdx.x & 127;                  // 256 threads, 2-way split over partials
    int half = threadIdx.x >> 7;
    float s = 0.f, s2 = 0.f;
    for (int b = half; b < nblk; b += 2) {
        s  += psum[b * 128 + c];
        s2 += psum2[b * 128 + c];
    }
    __shared__ float sm[256], sm2[256];
    sm[threadIdx.x] = s; sm2[threadIdx.x] = s2; __syncthreads();
    if (half == 0) {
        s  += sm[threadIdx.x + 128];
        s2 += sm2[threadIdx.x + 128];
        float mu = s * inv_n;
        float var = s2 * inv_n - mu * mu;
        float inv = rsqrtf(var + BN_EPS);
        float sc = gamma[c] * inv;
        scale[c] = sc;
        shift[c] = beta[c] - mu * sc;
    }
}

// ---------- final: out = relu(bn2(h2) + x) ----------
__global__ __launch_bounds__(256) void final_kernel(
    const float* __restrict__ h2, const float* __restrict__ x,
    const float* __restrict__ scale, const float* __restrict__ shift,
    float* __restrict__ out, int total)
{
    int i = blockIdx.x * 256 + threadIdx.x;
    if (i * 4 >= total) return;
    float4 hv = ((const float4*)h2)[i];
    float4 xv = ((const float4*)x)[i];
    int c = (i * 4) & 127;
    float4 o;
    o.x = fmaxf(hv.x * scale[c + 0] + shift[c + 0] + xv.x, 0.f);
    o.y = fmaxf(hv.y * scale[c + 1] + shift[c + 1] + xv.y, 0.f);
    o.z = fmaxf(hv.z * scale[c + 2] + shift[c + 2] + xv.z, 0.f);
    o.w = fmaxf(hv.w * scale[c + 3] + shift[c + 3] + xv.w, 0.f);
    ((float4*)out)[i] = o;
}

// ---------- launch ----------
extern "C" void kernel_launch(void* const* d_in, const int* in_sizes, int n_in,
                              void* d_out, int out_size, void* d_ws, size_t ws_size,
                              hipStream_t stream)
{
    const float* x    = (const float*)d_in[0];
    const int*   ei   = (const int*)  d_in[1];
    const float* Wl1  = (const float*)d_in[2];
    const float* Wr1  = (const float*)d_in[3];
    const float* att1 = (const float*)d_in[4];
    const float* b1   = (const float*)d_in[5];
    const float* g1   = (const float*)d_in[6];
    const float* be1  = (const float*)d_in[7];
    const float* Wl2  = (const float*)d_in[8];
    const float* Wr2  = (const float*)d_in[9];
    const float* att2 = (const float*)d_in[10];
    const float* b2   = (const float*)d_in[11];
    const float* g2   = (const float*)d_in[12];
    const float* be2  = (const float*)d_in[13];
    float* out = (float*)d_out;

    int n = in_sizes[0] / D;
    int E = in_sizes[1] / 2;
    const int* e_src = ei;
    const int* e_dst = ei + E;

    char* w = (char*)d_ws;
    auto alloc = [&](size_t bytes) -> char* {
        char* p = w;
        w += (bytes + 255) / 256 * 256;
        return p;
    };
    unsigned short* xl = (unsigned short*)alloc((size_t)n * D * 2);
    float* xr          = (float*)alloc((size_t)n * D * 4);
    float* h           = (float*)alloc((size_t)n * D * 4);
    int* row_start     = (int*)alloc((size_t)(n + 1) * 4);
    int* cnt           = (int*)alloc((size_t)n * 4);
    int* cursor        = (int*)alloc((size_t)n * 4);
    int* esrc          = (int*)alloc((size_t)(E + 8) * 4);
    int* bsum          = (int*)alloc(256 * 4);
    float* bn          = (float*)alloc(4 * 128 * 4);      // scale1, shift1, scale2, shift2
    float* psum        = (float*)alloc((size_t)BN_BLOCKS * 128 * 4);
    float* psum2       = (float*)alloc((size_t)BN_BLOCKS * 128 * 4);
    unsigned short* Bp1 = (unsigned short*)alloc(32768 * 2);
    unsigned short* Bp2 = (unsigned short*)alloc(32768 * 2);

    int nb = (n + 255) / 256;
    int gemm_blocks = (((n + 31) / 32) + 3) / 4;

    zero_kernel<<<(n + 255) / 256, 256, 0, stream>>>(cnt, n, esrc + E);
    hist_kernel<<<(E + 255) / 256, 256, 0, stream>>>(e_dst, cnt, E);
    scan_block<<<nb, 256, 0, stream>>>(cnt, row_start, bsum, n);
    scan_bsum<<<1, 256, 0, stream>>>(bsum, nb);
    scan_fix<<<nb, 256, 0, stream>>>(row_start, bsum, cursor, n);
    scatter_kernel<<<(E + 255) / 256, 256, 0, stream>>>(e_src, e_dst, cursor, esrc, E);
    repack_w<<<128, 256, 0, stream>>>(Wl1, Wr1, Bp1);
    repack_w<<<128, 256, 0, stream>>>(Wl2, Wr2, Bp2);

    // layer 1
    gemm_mfma<false><<<gemm_blocks, 256, 0, stream>>>(x, Bp1, nullptr, nullptr, xl, xr, n);
    gat_kernel<<<(n + 3) / 4, 256, 0, stream>>>(xl, xr, att1, b1, row_start, esrc, h, n);
    bn_stats<<<BN_BLOCKS, 256, 0, stream>>>(h, psum, psum2, n);
    bn_final<<<1, 256, 0, stream>>>(psum, psum2, g1, be1, bn + 0, bn + 128, 1.0f / n, BN_BLOCKS);

    // layer 2 (BN1+ReLU fused into GEMM A-load)
    gemm_mfma<true><<<gemm_blocks, 256, 0, stream>>>(h, Bp2, bn + 0, bn + 128, xl, xr, n);
    gat_kernel<<<(n + 3) / 4, 256, 0, stream>>>(xl, xr, att2, b2, row_start, esrc, h, n);
    bn_stats<<<BN_BLOCKS, 256, 0, stream>>>(h, psum, psum2, n);
    bn_final<<<1, 256, 0, stream>>>(psum, psum2, g2, be2, bn + 256, bn + 384, 1.0f / n, BN_BLOCKS);

    final_kernel<<<((n * D / 4) + 255) / 256, 256, 0, stream>>>(h, x, bn + 256, bn + 384, out, n * D);
}

// Round 6
// 279.918 us; speedup vs baseline: 1.7004x; 1.4326x over previous
//
#include <hip/hip_runtime.h>
#include <cstdint>
#include <cstddef>

#define D 128
#define BN_EPS 1e-5f
#define NEG_INF -3.0e38f
#define BN_BLOCKS 512

typedef __attribute__((ext_vector_type(8))) short bf16x8;
typedef __attribute__((ext_vector_type(4))) float f32x4;

// ---------- helpers ----------
static __device__ __forceinline__ unsigned short f2bf(float f) {
    uint32_t u = __float_as_uint(f);
    uint32_t r = (u + 0x7fffu + ((u >> 16) & 1u)) >> 16;
    return (unsigned short)r;
}

// sum across each 16-lane row via DPP adds (no LDS/DS ops)
static __device__ __forceinline__ float hsum16(float x) {
    x += __int_as_float(__builtin_amdgcn_update_dpp(0, __float_as_int(x), 0xB1, 0xF, 0xF, true));
    x += __int_as_float(__builtin_amdgcn_update_dpp(0, __float_as_int(x), 0x4E, 0xF, 0xF, true));
    x += __int_as_float(__builtin_amdgcn_update_dpp(0, __float_as_int(x), 0x124, 0xF, 0xF, true));
    x += __int_as_float(__builtin_amdgcn_update_dpp(0, __float_as_int(x), 0x128, 0xF, 0xF, true));
    return x;
}

// ---------- zero ----------
__global__ void zero_kernel(int* cnt, int n, int* esrc_tail) {
    int i = blockIdx.x * 256 + threadIdx.x;
    if (i < n) cnt[i] = 0;
    if (i < 16) esrc_tail[i] = 0;
}

// ---------- CSR build ----------
__global__ void hist_kernel(const int* __restrict__ dst, int* __restrict__ cnt, int E) {
    int e = blockIdx.x * 256 + threadIdx.x;
    if (e < E) atomicAdd(&cnt[dst[e]], 1);
}

__global__ void scan_block(const int* __restrict__ cnt, int* __restrict__ row_start,
                           int* __restrict__ bsum, int n) {
    __shared__ int tmp[256];
    int tid = threadIdx.x;
    int i = blockIdx.x * 256 + tid;
    int v = (i < n) ? cnt[i] : 0;
    tmp[tid] = v; __syncthreads();
    for (int off = 1; off < 256; off <<= 1) {
        int t = (tid >= off) ? tmp[tid - off] : 0;
        __syncthreads();
        tmp[tid] += t; __syncthreads();
    }
    if (i < n) row_start[i + 1] = tmp[tid];
    if (tid == 255) bsum[blockIdx.x] = tmp[255];
}

__global__ void scan_bsum(int* bsum, int nb) {
    __shared__ int tmp[256];
    int tid = threadIdx.x;
    int v = (tid < nb) ? bsum[tid] : 0;
    tmp[tid] = v; __syncthreads();
    for (int off = 1; off < 256; off <<= 1) {
        int t = (tid >= off) ? tmp[tid - off] : 0;
        __syncthreads();
        tmp[tid] += t; __syncthreads();
    }
    if (tid < nb) bsum[tid] = tmp[tid];
}

__global__ void scan_fix(int* __restrict__ row_start, const int* __restrict__ bsum,
                         int* __restrict__ cursor, int n) {
    int i = blockIdx.x * 256 + threadIdx.x;
    if (i < n) {
        int add = (blockIdx.x > 0) ? bsum[blockIdx.x - 1] : 0;
        int val = row_start[i + 1] + add;
        row_start[i + 1] = val;
        if (i + 1 < n) cursor[i + 1] = val;
    }
    if (i == 0) { row_start[0] = 0; cursor[0] = 0; }
}

__global__ void scatter_kernel(const int* __restrict__ src, const int* __restrict__ dst,
                               int* __restrict__ cursor, int* __restrict__ esrc, int E) {
    int e = blockIdx.x * 256 + threadIdx.x;
    if (e < E) {
        int p = atomicAdd(&cursor[dst[e]], 1);
        esrc[p] = src[e];
    }
}

// ---------- weight repack into MFMA B-fragment order ----------
__global__ void repack_w(const float* __restrict__ Wl, const float* __restrict__ Wr,
                         unsigned short* __restrict__ Bp) {
    int idx = blockIdx.x * 256 + threadIdx.x;   // 0..32767
    int i    = idx & 7;
    int lane = (idx >> 3) & 63;
    int kt   = (idx >> 9) & 3;
    int jt   = idx >> 11;                        // 0..15
    int k   = kt * 32 + (lane >> 4) * 8 + i;
    int col = jt * 16 + (lane & 15);
    float v = (col < 128) ? Wl[k * 128 + col] : Wr[k * 128 + (col - 128)];
    Bp[idx] = f2bf(v);
}

// ---------- MFMA dual GEMM: [n x 128] @ [128 x 256] -> xl (bf16), xr (f32) ----------
template<bool BN>
__global__ __launch_bounds__(256, 2) void gemm_mfma(
    const float* __restrict__ X, const unsigned short* __restrict__ Bp,
    const float* __restrict__ scale, const float* __restrict__ shift,
    unsigned short* __restrict__ xl, float* __restrict__ xr, int n)
{
    __shared__ unsigned short smem[32768];      // 64KB: full fragment-ordered B
    {
        const float4* s = (const float4*)Bp;
        float4* d = (float4*)smem;
        #pragma unroll
        for (int it = 0; it < 16; ++it)
            d[it * 256 + threadIdx.x] = s[it * 256 + threadIdx.x];
    }
    __syncthreads();

    int wid = threadIdx.x >> 6, lane = threadIdx.x & 63;
    int nw = (n + 31) >> 5;
    int wrow = blockIdx.x * 4 + wid;
    if (wrow >= nw) return;                     // after barrier: safe
    int r0 = wrow * 32;
    int m = lane & 15, hi = lane >> 4;

    f32x4 accA[16], accB[16];
    #pragma unroll
    for (int jt = 0; jt < 16; ++jt) {
        accA[jt] = (f32x4){0.f, 0.f, 0.f, 0.f};
        accB[jt] = (f32x4){0.f, 0.f, 0.f, 0.f};
    }

    int rA = r0 + m;      if (rA > n - 1) rA = n - 1;
    int rB = r0 + 16 + m; if (rB > n - 1) rB = n - 1;
    const float* xrowA = X + (size_t)rA * D;
    const float* xrowB = X + (size_t)rB * D;

    #pragma unroll
    for (int kt = 0; kt < 4; ++kt) {
        int kb = kt * 32 + hi * 8;
        float sca[8], shf[8];
        if (BN) {
            float4 s0 = *(const float4*)(scale + kb);
            float4 s1 = *(const float4*)(scale + kb + 4);
            float4 h0 = *(const float4*)(shift + kb);
            float4 h1 = *(const float4*)(shift + kb + 4);
            sca[0]=s0.x; sca[1]=s0.y; sca[2]=s0.z; sca[3]=s0.w;
            sca[4]=s1.x; sca[5]=s1.y; sca[6]=s1.z; sca[7]=s1.w;
            shf[0]=h0.x; shf[1]=h0.y; shf[2]=h0.z; shf[3]=h0.w;
            shf[4]=h1.x; shf[5]=h1.y; shf[6]=h1.z; shf[7]=h1.w;
        }
        float4 a0 = *(const float4*)(xrowA + kb);
        float4 a1 = *(const float4*)(xrowA + kb + 4);
        float4 b0 = *(const float4*)(xrowB + kb);
        float4 b1 = *(const float4*)(xrowB + kb + 4);
        float avA[8] = {a0.x, a0.y, a0.z, a0.w, a1.x, a1.y, a1.z, a1.w};
        float avB[8] = {b0.x, b0.y, b0.z, b0.w, b1.x, b1.y, b1.z, b1.w};
        bf16x8 afragA, afragB;
        #pragma unroll
        for (int i = 0; i < 8; ++i) {
            float va = avA[i], vb = avB[i];
            if (BN) {
                va = fmaxf(va * sca[i] + shf[i], 0.f);
                vb = fmaxf(vb * sca[i] + shf[i], 0.f);
            }
            afragA[i] = (short)f2bf(va);
            afragB[i] = (short)f2bf(vb);
        }
        #pragma unroll
        for (int jt = 0; jt < 16; ++jt) {
            bf16x8 bfrag = *(const bf16x8*)(smem + (size_t)((jt * 4 + kt) * 64 + lane) * 8);
            accA[jt] = __builtin_amdgcn_mfma_f32_16x16x32_bf16(afragA, bfrag, accA[jt], 0, 0, 0);
            accB[jt] = __builtin_amdgcn_mfma_f32_16x16x32_bf16(afragB, bfrag, accB[jt], 0, 0, 0);
        }
    }

    // C/D layout: col = lane&15, row = (lane>>4)*4 + reg
    #pragma unroll
    for (int jt = 0; jt < 16; ++jt) {
        int col = jt * 16 + m;
        #pragma unroll
        for (int r = 0; r < 4; ++r) {
            int rowA = r0 + hi * 4 + r;
            int rowB = rowA + 16;
            if (rowA < n) {
                float v = accA[jt][r];
                if (jt < 8) xl[(size_t)rowA * D + col] = f2bf(v);
                else        xr[(size_t)rowA * D + (col - 128)] = v;
            }
            if (rowB < n) {
                float v = accB[jt][r];
                if (jt < 8) xl[(size_t)rowB * D + col] = f2bf(v);
                else        xr[(size_t)rowB * D + (col - 128)] = v;
            }
        }
    }
}

// ---------- node-centric GATv2: DPP reduce, 8-edge batches, software-pipelined gathers ----------
__global__ __launch_bounds__(256) void gat_kernel(
    const unsigned short* __restrict__ xl, const float* __restrict__ xr,
    const float* __restrict__ att, const float* __restrict__ bias,
    const int* __restrict__ row_start, const int* __restrict__ esrc,
    float* __restrict__ h, int n)
{
    const float L2E = 1.44269504089f;    // fold log2(e) into att: softmax invariant
    int wid = threadIdx.x >> 6;
    int lane = threadIdx.x & 63;
    int v = blockIdx.x * 4 + wid;
    if (v >= n) return;

    int c0 = lane * 2;
    const uint32_t* xl32 = (const uint32_t*)xl;   // 32-bit row offsets: u<<6 dwords
    int p = row_start[v], pe = row_start[v + 1];

    // prologue: issue batch-0 index loads + self/xr loads early
    uint32_t idxc[8];
    #pragma unroll
    for (int j = 0; j < 8; ++j) idxc[j] = (uint32_t)esrc[p + j];   // padded: always safe

    float a0 = att[c0] * L2E, a1 = att[c0 + 1] * L2E;
    float xr0 = xr[(size_t)v * D + c0];
    float xr1 = xr[(size_t)v * D + c0 + 1];
    uint32_t ws = xl32[((uint32_t)v << 6) + (uint32_t)lane];

    // batch-0 row gathers in flight during self-loop compute
    uint32_t wc[8];
    #pragma unroll
    for (int j = 0; j < 8; ++j) wc[j] = xl32[(idxc[j] << 6) + (uint32_t)lane];

    // self-loop initializes running max
    float sx0 = __uint_as_float(ws << 16);
    float sx1 = __uint_as_float(ws & 0xffff0000u);
    float t0 = sx0 + xr0; t0 = fmaxf(t0, 0.2f * t0);
    float t1 = sx1 + xr1; t1 = fmaxf(t1, 0.2f * t1);
    float m = hsum16(fmaf(a0, t0, a1 * t1));
    float den = 1.f;
    float acc0 = sx0, acc1 = sx1, acc0b = 0.f, acc1b = 0.f;

    for (int i = p; i < pe; i += 8) {
        int rem = pe - i;                        // wave-uniform
        // issue next-batch index loads (esrc padded by 16: safe)
        uint32_t idxn[8];
        #pragma unroll
        for (int j = 0; j < 8; ++j) idxn[j] = (uint32_t)esrc[i + 8 + j];

        // compute logits from current rows (covers idxn latency)
        float lg[8], x0v[8], x1v[8];
        #pragma unroll
        for (int j = 0; j < 8; ++j) {
            float x0 = __uint_as_float(wc[j] << 16);
            float x1 = __uint_as_float(wc[j] & 0xffff0000u);
            x0v[j] = x0; x1v[j] = x1;
            float f0 = x0 + xr0; f0 = fmaxf(f0, 0.2f * f0);
            float f1 = x1 + xr1; f1 = fmaxf(f1, 0.2f * f1);
            lg[j] = hsum16(fmaf(a0, f0, a1 * f1));
        }

        // issue next-batch row gathers (in flight during update phase)
        uint32_t wn[8];
        #pragma unroll
        for (int j = 0; j < 8; ++j) wn[j] = xl32[(idxn[j] << 6) + (uint32_t)lane];

        // online-softmax update
        #pragma unroll
        for (int j = 0; j < 8; ++j) if (j >= rem) lg[j] = NEG_INF;
        float mx = fmaxf(fmaxf(fmaxf(lg[0], lg[1]), fmaxf(lg[2], lg[3])),
                         fmaxf(fmaxf(lg[4], lg[5]), fmaxf(lg[6], lg[7])));
        if (__any(mx > m + 8.f)) {               // rare: rescale once per batch
            float nm = fmaxf(m, mx);
            float sc = exp2f(m - nm);
            den *= sc; acc0 *= sc; acc1 *= sc; acc0b *= sc; acc1b *= sc;
            m = nm;
        }
        float pex[8];
        #pragma unroll
        for (int j = 0; j < 8; ++j) pex[j] = exp2f(lg[j] - m);   // tail -> 0
        den += ((pex[0] + pex[1]) + (pex[2] + pex[3])) + ((pex[4] + pex[5]) + (pex[6] + pex[7]));
        #pragma unroll
        for (int j = 0; j < 8; j += 2) {
            acc0  = fmaf(pex[j],     x0v[j],     acc0);
            acc1  = fmaf(pex[j],     x1v[j],     acc1);
            acc0b = fmaf(pex[j + 1], x0v[j + 1], acc0b);
            acc1b = fmaf(pex[j + 1], x1v[j + 1], acc1b);
        }
        #pragma unroll
        for (int j = 0; j < 8; ++j) wc[j] = wn[j];
    }
    float inv = 1.0f / den;
    h[(size_t)v * D + c0]     = (acc0 + acc0b) * inv + bias[c0];
    h[(size_t)v * D + c0 + 1] = (acc1 + acc1b) * inv + bias[c0 + 1];
}

// ---------- BN stats: BW-shaped. 8 rows/block/iter as float4, LDS tree reduce ----------
__global__ __launch_bounds__(256) void bn_stats(const float* __restrict__ h,
                                                float* __restrict__ psum, float* __restrict__ psum2, int n)
{
    int c4 = threadIdx.x & 31;   // float4 slot within a row (channels c4*4..c4*4+3)
    int ty = threadIdx.x >> 5;   // row slot 0..7
    float sx = 0.f, sy = 0.f, sz = 0.f, sw = 0.f;
    float qx = 0.f, qy = 0.f, qz = 0.f, qw = 0.f;
    for (int r = blockIdx.x * 8 + ty; r < n; r += gridDim.x * 8) {
        float4 v = *(const float4*)(h + (size_t)r * D + c4 * 4);
        sx += v.x; sy += v.y; sz += v.z; sw += v.w;
        qx = fmaf(v.x, v.x, qx); qy = fmaf(v.y, v.y, qy);
        qz = fmaf(v.z, v.z, qz); qw = fmaf(v.w, v.w, qw);
    }
    __shared__ float4 smA[256], smB[256];
    smA[threadIdx.x] = make_float4(sx, sy, sz, sw);
    smB[threadIdx.x] = make_float4(qx, qy, qz, qw);
    __syncthreads();
    #pragma unroll
    for (int off = 128; off >= 32; off >>= 1) {
        if (threadIdx.x < off) {
            float4 a = smA[threadIdx.x], b = smA[threadIdx.x + off];
            smA[threadIdx.x] = make_float4(a.x + b.x, a.y + b.y, a.z + b.z, a.w + b.w);
            float4 c = smB[threadIdx.x], d2 = smB[threadIdx.x + off];
            smB[threadIdx.x] = make_float4(c.x + d2.x, c.y + d2.y, c.z + d2.z, c.w + d2.w);
        }
        __syncthreads();
    }
    if (threadIdx.x < 32) {
        ((float4*)psum)[blockIdx.x * 32 + threadIdx.x]  = smA[threadIdx.x];
        ((float4*)psum2)[blockIdx.x * 32 + threadIdx.x] = smB[threadIdx.x];
    }
}

// ---------- BN mid-reduce: psum[512][128] -> pmid[16][128] (coalesced float4) ----------
__global__ __launch_bounds__(256) void bn_mid(const float* __restrict__ psum, const float* __restrict__ psum2,
                                              float* __restrict__ pmid, float* __restrict__ pmid2)
{
    int c4 = threadIdx.x & 31;
    int rg = threadIdx.x >> 5;   // 0..7
    float4 s = make_float4(0.f, 0.f, 0.f, 0.f), q = make_float4(0.f, 0.f, 0.f, 0.f);
    #pragma unroll
    for (int k = 0; k < 4; ++k) {
        int r = blockIdx.x * 32 + rg + k * 8;
        float4 a = ((const float4*)psum)[r * 32 + c4];
        float4 b = ((const float4*)psum2)[r * 32 + c4];
        s.x += a.x; s.y += a.y; s.z += a.z; s.w += a.w;
        q.x += b.x; q.y += b.y; q.z += b.z; q.w += b.w;
    }
    __shared__ float4 smA[256], smB[256];
    smA[threadIdx.x] = s; smB[threadIdx.x] = q;
    __syncthreads();
    #pragma unroll
    for (int off = 128; off >= 32; off >>= 1) {
        if (threadIdx.x < off) {
            float4 a = smA[threadIdx.x], b = smA[threadIdx.x + off];
            smA[threadIdx.x] = make_float4(a.x + b.x, a.y + b.y, a.z + b.z, a.w + b.w);
            float4 c = smB[threadIdx.x], d2 = smB[threadIdx.x + off];
            smB[threadIdx.x] = make_float4(c.x + d2.x, c.y + d2.y, c.z + d2.z, c.w + d2.w);
        }
        __syncthreads();
    }
    if (threadIdx.x < 32) {
        ((float4*)pmid)[blockIdx.x * 32 + threadIdx.x]  = smA[threadIdx.x];
        ((float4*)pmid2)[blockIdx.x * 32 + threadIdx.x] = smB[threadIdx.x];
    }
}

__global__ void bn_final(const float* __restrict__ psum, const float* __restrict__ psum2,
                         const float* __restrict__ gamma, const float* __restrict__ beta,
                         float* __restrict__ scale, float* __restrict__ shift,
                         float inv_n, int nblk)
{
    int c = threadIdx.x & 127;                  // 256 threads, 2-way split over partials
    int half = threadIdx.x >> 7;
    float s = 0.f, s2 = 0.f;
    for (int b = half; b < nblk; b += 2) {
        s  += psum[b * 128 + c];
        s2 += psum2[b * 128 + c];
    }
    __shared__ float sm[256], sm2[256];
    sm[threadIdx.x] = s; sm2[threadIdx.x] = s2; __syncthreads();
    if (half == 0) {
        s  += sm[threadIdx.x + 128];
        s2 += sm2[threadIdx.x + 128];
        float mu = s * inv_n;
        float var = s2 * inv_n - mu * mu;
        float inv = rsqrtf(var + BN_EPS);
        float sc = gamma[c] * inv;
        scale[c] = sc;
        shift[c] = beta[c] - mu * sc;
    }
}

// ---------- final: out = relu(bn2(h2) + x) ----------
__global__ __launch_bounds__(256) void final_kernel(
    const float* __restrict__ h2, const float* __restrict__ x,
    const float* __restrict__ scale, const float* __restrict__ shift,
    float* __restrict__ out, int total)
{
    int i = blockIdx.x * 256 + threadIdx.x;
    if (i * 4 >= total) return;
    float4 hv = ((const float4*)h2)[i];
    float4 xv = ((const float4*)x)[i];
    int c = (i * 4) & 127;
    float4 o;
    o.x = fmaxf(hv.x * scale[c + 0] + shift[c + 0] + xv.x, 0.f);
    o.y = fmaxf(hv.y * scale[c + 1] + shift[c + 1] + xv.y, 0.f);
    o.z = fmaxf(hv.z * scale[c + 2] + shift[c + 2] + xv.z, 0.f);
    o.w = fmaxf(hv.w * scale[c + 3] + shift[c + 3] + xv.w, 0.f);
    ((float4*)out)[i] = o;
}

// ---------- launch ----------
extern "C" void kernel_launch(void* const* d_in, const int* in_sizes, int n_in,
                              void* d_out, int out_size, void* d_ws, size_t ws_size,
                              hipStream_t stream)
{
    const float* x    = (const float*)d_in[0];
    const int*   ei   = (const int*)  d_in[1];
    const float* Wl1  = (const float*)d_in[2];
    const float* Wr1  = (const float*)d_in[3];
    const float* att1 = (const float*)d_in[4];
    const float* b1   = (const float*)d_in[5];
    const float* g1   = (const float*)d_in[6];
    const float* be1  = (const float*)d_in[7];
    const float* Wl2  = (const float*)d_in[8];
    const float* Wr2  = (const float*)d_in[9];
    const float* att2 = (const float*)d_in[10];
    const float* b2   = (const float*)d_in[11];
    const float* g2   = (const float*)d_in[12];
    const float* be2  = (const float*)d_in[13];
    float* out = (float*)d_out;

    int n = in_sizes[0] / D;
    int E = in_sizes[1] / 2;
    const int* e_src = ei;
    const int* e_dst = ei + E;

    char* w = (char*)d_ws;
    auto alloc = [&](size_t bytes) -> char* {
        char* p = w;
        w += (bytes + 255) / 256 * 256;
        return p;
    };
    unsigned short* xl = (unsigned short*)alloc((size_t)n * D * 2);
    float* xr          = (float*)alloc((size_t)n * D * 4);
    float* h           = (float*)alloc((size_t)n * D * 4);
    int* row_start     = (int*)alloc((size_t)(n + 1) * 4);
    int* cnt           = (int*)alloc((size_t)n * 4);
    int* cursor        = (int*)alloc((size_t)n * 4);
    int* esrc          = (int*)alloc((size_t)(E + 16) * 4);
    int* bsum          = (int*)alloc(256 * 4);
    float* bn          = (float*)alloc(4 * 128 * 4);      // scale1, shift1, scale2, shift2
    float* psum        = (float*)alloc((size_t)BN_BLOCKS * 128 * 4);
    float* psum2       = (float*)alloc((size_t)BN_BLOCKS * 128 * 4);
    float* pmid        = (float*)alloc(16 * 128 * 4);
    float* pmid2       = (float*)alloc(16 * 128 * 4);
    unsigned short* Bp1 = (unsigned short*)alloc(32768 * 2);
    unsigned short* Bp2 = (unsigned short*)alloc(32768 * 2);

    int nb = (n + 255) / 256;
    int gemm_blocks = (((n + 31) / 32) + 3) / 4;

    zero_kernel<<<(n + 255) / 256, 256, 0, stream>>>(cnt, n, esrc + E);
    hist_kernel<<<(E + 255) / 256, 256, 0, stream>>>(e_dst, cnt, E);
    scan_block<<<nb, 256, 0, stream>>>(cnt, row_start, bsum, n);
    scan_bsum<<<1, 256, 0, stream>>>(bsum, nb);
    scan_fix<<<nb, 256, 0, stream>>>(row_start, bsum, cursor, n);
    scatter_kernel<<<(E + 255) / 256, 256, 0, stream>>>(e_src, e_dst, cursor, esrc, E);
    repack_w<<<128, 256, 0, stream>>>(Wl1, Wr1, Bp1);
    repack_w<<<128, 256, 0, stream>>>(Wl2, Wr2, Bp2);

    // layer 1
    gemm_mfma<false><<<gemm_blocks, 256, 0, stream>>>(x, Bp1, nullptr, nullptr, xl, xr, n);
    gat_kernel<<<(n + 3) / 4, 256, 0, stream>>>(xl, xr, att1, b1, row_start, esrc, h, n);
    bn_stats<<<BN_BLOCKS, 256, 0, stream>>>(h, psum, psum2, n);
    bn_mid<<<16, 256, 0, stream>>>(psum, psum2, pmid, pmid2);
    bn_final<<<1, 256, 0, stream>>>(pmid, pmid2, g1, be1, bn + 0, bn + 128, 1.0f / n, 16);

    // layer 2 (BN1+ReLU fused into GEMM A-load)
    gemm_mfma<true><<<gemm_blocks, 256, 0, stream>>>(h, Bp2, bn + 0, bn + 128, xl, xr, n);
    gat_kernel<<<(n + 3) / 4, 256, 0, stream>>>(xl, xr, att2, b2, row_start, esrc, h, n);
    bn_stats<<<BN_BLOCKS, 256, 0, stream>>>(h, psum, psum2, n);
    bn_mid<<<16, 256, 0, stream>>>(psum, psum2, pmid, pmid2);
    bn_final<<<1, 256, 0, stream>>>(pmid, pmid2, g2, be2, bn + 256, bn + 384, 1.0f / n, 16);

    final_kernel<<<((n * D / 4) + 255) / 256, 256, 0, stream>>>(h, x, bn + 256, bn + 384, out, n * D);
}

// Round 7
// 264.993 us; speedup vs baseline: 1.7961x; 1.0563x over previous
//
#include <hip/hip_runtime.h>
#include <cstdint>
#include <cstddef>

#define D 128
#define BN_EPS 1e-5f
#define NEG_INF -3.0e38f
#define BN_BLOCKS 512

typedef __attribute__((ext_vector_type(8))) short bf16x8;
typedef __attribute__((ext_vector_type(4))) float f32x4;

// ---------- helpers ----------
static __device__ __forceinline__ unsigned short f2bf(float f) {
    uint32_t u = __float_as_uint(f);
    uint32_t r = (u + 0x7fffu + ((u >> 16) & 1u)) >> 16;
    return (unsigned short)r;
}

// sum within each quad (4 lanes) via DPP adds
static __device__ __forceinline__ float qsum4(float x) {
    x += __int_as_float(__builtin_amdgcn_update_dpp(0, __float_as_int(x), 0xB1, 0xF, 0xF, true));
    x += __int_as_float(__builtin_amdgcn_update_dpp(0, __float_as_int(x), 0x4E, 0xF, 0xF, true));
    return x;
}

// ---------- zero ----------
__global__ void zero_kernel(int* cnt, int n, int* esrc_tail) {
    int i = blockIdx.x * 256 + threadIdx.x;
    if (i < n) cnt[i] = 0;
    if (i < 16) esrc_tail[i] = 0;
}

// ---------- CSR build ----------
__global__ void hist_kernel(const int* __restrict__ dst, int* __restrict__ cnt, int E) {
    int e = blockIdx.x * 256 + threadIdx.x;
    if (e < E) atomicAdd(&cnt[dst[e]], 1);
}

__global__ void scan_block(const int* __restrict__ cnt, int* __restrict__ row_start,
                           int* __restrict__ bsum, int n) {
    __shared__ int tmp[256];
    int tid = threadIdx.x;
    int i = blockIdx.x * 256 + tid;
    int v = (i < n) ? cnt[i] : 0;
    tmp[tid] = v; __syncthreads();
    for (int off = 1; off < 256; off <<= 1) {
        int t = (tid >= off) ? tmp[tid - off] : 0;
        __syncthreads();
        tmp[tid] += t; __syncthreads();
    }
    if (i < n) row_start[i + 1] = tmp[tid];
    if (tid == 255) bsum[blockIdx.x] = tmp[255];
}

__global__ void scan_bsum(int* bsum, int nb) {
    __shared__ int tmp[256];
    int tid = threadIdx.x;
    int v = (tid < nb) ? bsum[tid] : 0;
    tmp[tid] = v; __syncthreads();
    for (int off = 1; off < 256; off <<= 1) {
        int t = (tid >= off) ? tmp[tid - off] : 0;
        __syncthreads();
        tmp[tid] += t; __syncthreads();
    }
    if (tid < nb) bsum[tid] = tmp[tid];
}

__global__ void scan_fix(int* __restrict__ row_start, const int* __restrict__ bsum,
                         int* __restrict__ cursor, int n) {
    int i = blockIdx.x * 256 + threadIdx.x;
    if (i < n) {
        int add = (blockIdx.x > 0) ? bsum[blockIdx.x - 1] : 0;
        int val = row_start[i + 1] + add;
        row_start[i + 1] = val;
        if (i + 1 < n) cursor[i + 1] = val;
    }
    if (i == 0) { row_start[0] = 0; cursor[0] = 0; }
}

__global__ void scatter_kernel(const int* __restrict__ src, const int* __restrict__ dst,
                               int* __restrict__ cursor, int* __restrict__ esrc, int E) {
    int e = blockIdx.x * 256 + threadIdx.x;
    if (e < E) {
        int p = atomicAdd(&cursor[dst[e]], 1);
        esrc[p] = src[e];
    }
}

// ---------- weight repack into MFMA B-fragment order ----------
__global__ void repack_w(const float* __restrict__ Wl, const float* __restrict__ Wr,
                         unsigned short* __restrict__ Bp) {
    int idx = blockIdx.x * 256 + threadIdx.x;   // 0..32767
    int i    = idx & 7;
    int lane = (idx >> 3) & 63;
    int kt   = (idx >> 9) & 3;
    int jt   = idx >> 11;                        // 0..15
    int k   = kt * 32 + (lane >> 4) * 8 + i;
    int col = jt * 16 + (lane & 15);
    float v = (col < 128) ? Wl[k * 128 + col] : Wr[k * 128 + (col - 128)];
    Bp[idx] = f2bf(v);
}

// ---------- MFMA dual GEMM: [n x 128] @ [128 x 256] -> xl (bf16), xr (f32) ----------
template<bool BN>
__global__ __launch_bounds__(256, 2) void gemm_mfma(
    const float* __restrict__ X, const unsigned short* __restrict__ Bp,
    const float* __restrict__ scale, const float* __restrict__ shift,
    unsigned short* __restrict__ xl, float* __restrict__ xr, int n)
{
    __shared__ unsigned short smem[32768];      // 64KB: full fragment-ordered B
    {
        const float4* s = (const float4*)Bp;
        float4* d = (float4*)smem;
        #pragma unroll
        for (int it = 0; it < 16; ++it)
            d[it * 256 + threadIdx.x] = s[it * 256 + threadIdx.x];
    }
    __syncthreads();

    int wid = threadIdx.x >> 6, lane = threadIdx.x & 63;
    int nw = (n + 31) >> 5;
    int wrow = blockIdx.x * 4 + wid;
    if (wrow >= nw) return;                     // after barrier: safe
    int r0 = wrow * 32;
    int m = lane & 15, hi = lane >> 4;

    f32x4 accA[16], accB[16];
    #pragma unroll
    for (int jt = 0; jt < 16; ++jt) {
        accA[jt] = (f32x4){0.f, 0.f, 0.f, 0.f};
        accB[jt] = (f32x4){0.f, 0.f, 0.f, 0.f};
    }

    int rA = r0 + m;      if (rA > n - 1) rA = n - 1;
    int rB = r0 + 16 + m; if (rB > n - 1) rB = n - 1;
    const float* xrowA = X + (size_t)rA * D;
    const float* xrowB = X + (size_t)rB * D;

    #pragma unroll
    for (int kt = 0; kt < 4; ++kt) {
        int kb = kt * 32 + hi * 8;
        float sca[8], shf[8];
        if (BN) {
            float4 s0 = *(const float4*)(scale + kb);
            float4 s1 = *(const float4*)(scale + kb + 4);
            float4 h0 = *(const float4*)(shift + kb);
            float4 h1 = *(const float4*)(shift + kb + 4);
            sca[0]=s0.x; sca[1]=s0.y; sca[2]=s0.z; sca[3]=s0.w;
            sca[4]=s1.x; sca[5]=s1.y; sca[6]=s1.z; sca[7]=s1.w;
            shf[0]=h0.x; shf[1]=h0.y; shf[2]=h0.z; shf[3]=h0.w;
            shf[4]=h1.x; shf[5]=h1.y; shf[6]=h1.z; shf[7]=h1.w;
        }
        float4 a0 = *(const float4*)(xrowA + kb);
        float4 a1 = *(const float4*)(xrowA + kb + 4);
        float4 b0 = *(const float4*)(xrowB + kb);
        float4 b1 = *(const float4*)(xrowB + kb + 4);
        float avA[8] = {a0.x, a0.y, a0.z, a0.w, a1.x, a1.y, a1.z, a1.w};
        float avB[8] = {b0.x, b0.y, b0.z, b0.w, b1.x, b1.y, b1.z, b1.w};
        bf16x8 afragA, afragB;
        #pragma unroll
        for (int i = 0; i < 8; ++i) {
            float va = avA[i], vb = avB[i];
            if (BN) {
                va = fmaxf(va * sca[i] + shf[i], 0.f);
                vb = fmaxf(vb * sca[i] + shf[i], 0.f);
            }
            afragA[i] = (short)f2bf(va);
            afragB[i] = (short)f2bf(vb);
        }
        #pragma unroll
        for (int jt = 0; jt < 16; ++jt) {
            bf16x8 bfrag = *(const bf16x8*)(smem + (size_t)((jt * 4 + kt) * 64 + lane) * 8);
            accA[jt] = __builtin_amdgcn_mfma_f32_16x16x32_bf16(afragA, bfrag, accA[jt], 0, 0, 0);
            accB[jt] = __builtin_amdgcn_mfma_f32_16x16x32_bf16(afragB, bfrag, accB[jt], 0, 0, 0);
        }
    }

    // C/D layout: col = lane&15, row = (lane>>4)*4 + reg
    #pragma unroll
    for (int jt = 0; jt < 16; ++jt) {
        int col = jt * 16 + m;
        #pragma unroll
        for (int r = 0; r < 4; ++r) {
            int rowA = r0 + hi * 4 + r;
            int rowB = rowA + 16;
            if (rowA < n) {
                float v = accA[jt][r];
                if (jt < 8) xl[(size_t)rowA * D + col] = f2bf(v);
                else        xr[(size_t)rowA * D + (col - 128)] = v;
            }
            if (rowB < n) {
                float v = accB[jt][r];
                if (jt < 8) xl[(size_t)rowB * D + col] = f2bf(v);
                else        xr[(size_t)rowB * D + (col - 128)] = v;
            }
        }
    }
}

// ---------- node-centric GATv2: 16 lanes/edge, 4 edge streams/wave ----------
// lane = g*16 + il : group g owns edge stream, lane covers channels il*8..il*8+7.
// Each group keeps an independent online-softmax partial (m, den, acc[8]);
// partials merged at the end with the standard softmax-merge.
__global__ __launch_bounds__(256) void gat_kernel(
    const unsigned short* __restrict__ xl, const float* __restrict__ xr,
    const float* __restrict__ att, const float* __restrict__ bias,
    const int* __restrict__ row_start, const int* __restrict__ esrc,
    float* __restrict__ h, int n)
{
    const float L2E = 1.44269504089f;    // fold log2(e) into att: softmax invariant
    int wid = threadIdx.x >> 6;
    int lane = threadIdx.x & 63;
    int v = blockIdx.x * 4 + wid;
    if (v >= n) return;
    int g  = lane >> 4;                  // edge-slot group
    int il = lane & 15;                  // channel block

    // per-lane node data: xr and att for channels il*8..il*8+7
    float xrv[8], av[8];
    {
        float4 xa = *(const float4*)(xr + (size_t)v * D + il * 8);
        float4 xb = *(const float4*)(xr + (size_t)v * D + il * 8 + 4);
        xrv[0]=xa.x; xrv[1]=xa.y; xrv[2]=xa.z; xrv[3]=xa.w;
        xrv[4]=xb.x; xrv[5]=xb.y; xrv[6]=xb.z; xrv[7]=xb.w;
        float4 aa = *(const float4*)(att + il * 8);
        float4 ab = *(const float4*)(att + il * 8 + 4);
        av[0]=aa.x*L2E; av[1]=aa.y*L2E; av[2]=aa.z*L2E; av[3]=aa.w*L2E;
        av[4]=ab.x*L2E; av[5]=ab.y*L2E; av[6]=ab.z*L2E; av[7]=ab.w*L2E;
    }

    int p = row_start[v];
    int deg = row_start[v + 1] - p;
    int vcnt = deg + 1;                  // virtual edges incl. self-loop

    float m = NEG_INF, den = 0.f;
    float acc[8] = {0.f, 0.f, 0.f, 0.f, 0.f, 0.f, 0.f, 0.f};

    auto process = [&](uint4 q, bool valid) {
        float x[8];
        x[0] = __uint_as_float(q.x << 16); x[1] = __uint_as_float(q.x & 0xffff0000u);
        x[2] = __uint_as_float(q.y << 16); x[3] = __uint_as_float(q.y & 0xffff0000u);
        x[4] = __uint_as_float(q.z << 16); x[5] = __uint_as_float(q.z & 0xffff0000u);
        x[6] = __uint_as_float(q.w << 16); x[7] = __uint_as_float(q.w & 0xffff0000u);
        float d = 0.f;
        #pragma unroll
        for (int k = 0; k < 8; ++k) {
            float f = x[k] + xrv[k];
            f = fmaxf(f, 0.2f * f);      // LeakyReLU
            d = fmaf(av[k], f, d);
        }
        d = qsum4(d);                    // per-head logit (quad-uniform)
        float lg = valid ? d : NEG_INF;
        if (__any(lg > m + 8.f)) {       // rare: deferred-max rescale
            float nm = fmaxf(m, lg);
            float sc = exp2f(m - nm);
            den *= sc;
            #pragma unroll
            for (int k = 0; k < 8; ++k) acc[k] *= sc;
            m = nm;
        }
        float pex = valid ? exp2f(lg - m) : 0.f;
        den += pex;
        #pragma unroll
        for (int k = 0; k < 8; ++k) acc[k] = fmaf(pex, x[k], acc[k]);
    };

    // iteration 0: group 0 takes the self-loop, groups 1..3 take edges 0..2
    {
        uint32_t u0 = (g == 0) ? (uint32_t)v : (uint32_t)esrc[p + g - 1]; // pad-safe
        bool val0 = g < vcnt;
        uint4 q0 = *(const uint4*)(xl + ((size_t)u0 << 7) + il * 8);
        process(q0, val0);
    }
    // remaining edges, 8 virtual per loop (two 4-wide sub-iters, gathers co-issued)
    for (int base = 4; base < vcnt; base += 8) {
        int iA = base + g, iB = base + 4 + g;
        bool vA = iA < vcnt, vB = iB < vcnt;
        uint32_t uA = vA ? (uint32_t)esrc[p + iA - 1] : 0u;
        uint32_t uB = vB ? (uint32_t)esrc[p + iB - 1] : 0u;
        uint4 qA = *(const uint4*)(xl + ((size_t)uA << 7) + il * 8);
        uint4 qB = *(const uint4*)(xl + ((size_t)uB << 7) + il * 8);
        process(qA, vA);
        process(qB, vB);
    }

    // merge the 4 group partials (softmax merge over lane-xor 16/32)
    float m2 = fmaxf(m, __shfl_xor(m, 16));
    float M  = fmaxf(m2, __shfl_xor(m2, 32));
    float sc = exp2f(m - M);             // 0 for empty groups (m = -3e38)
    den *= sc;
    den += __shfl_xor(den, 16);
    den += __shfl_xor(den, 32);
    #pragma unroll
    for (int k = 0; k < 8; ++k) {
        acc[k] *= sc;
        acc[k] += __shfl_xor(acc[k], 16);
        acc[k] += __shfl_xor(acc[k], 32);
    }
    if (g == 0) {
        float inv = 1.f / den;
        float4 ba = *(const float4*)(bias + il * 8);
        float4 bb = *(const float4*)(bias + il * 8 + 4);
        float4 o0, o1;
        o0.x = fmaf(acc[0], inv, ba.x); o0.y = fmaf(acc[1], inv, ba.y);
        o0.z = fmaf(acc[2], inv, ba.z); o0.w = fmaf(acc[3], inv, ba.w);
        o1.x = fmaf(acc[4], inv, bb.x); o1.y = fmaf(acc[5], inv, bb.y);
        o1.z = fmaf(acc[6], inv, bb.z); o1.w = fmaf(acc[7], inv, bb.w);
        *(float4*)(h + (size_t)v * D + il * 8)     = o0;
        *(float4*)(h + (size_t)v * D + il * 8 + 4) = o1;
    }
}

// ---------- BN stats: BW-shaped. 8 rows/block/iter as float4, LDS tree reduce ----------
__global__ __launch_bounds__(256) void bn_stats(const float* __restrict__ h,
                                                float* __restrict__ psum, float* __restrict__ psum2, int n)
{
    int c4 = threadIdx.x & 31;   // float4 slot within a row (channels c4*4..c4*4+3)
    int ty = threadIdx.x >> 5;   // row slot 0..7
    float sx = 0.f, sy = 0.f, sz = 0.f, sw = 0.f;
    float qx = 0.f, qy = 0.f, qz = 0.f, qw = 0.f;
    for (int r = blockIdx.x * 8 + ty; r < n; r += gridDim.x * 8) {
        float4 v = *(const float4*)(h + (size_t)r * D + c4 * 4);
        sx += v.x; sy += v.y; sz += v.z; sw += v.w;
        qx = fmaf(v.x, v.x, qx); qy = fmaf(v.y, v.y, qy);
        qz = fmaf(v.z, v.z, qz); qw = fmaf(v.w, v.w, qw);
    }
    __shared__ float4 smA[256], smB[256];
    smA[threadIdx.x] = make_float4(sx, sy, sz, sw);
    smB[threadIdx.x] = make_float4(qx, qy, qz, qw);
    __syncthreads();
    #pragma unroll
    for (int off = 128; off >= 32; off >>= 1) {
        if (threadIdx.x < off) {
            float4 a = smA[threadIdx.x], b = smA[threadIdx.x + off];
            smA[threadIdx.x] = make_float4(a.x + b.x, a.y + b.y, a.z + b.z, a.w + b.w);
            float4 c = smB[threadIdx.x], d2 = smB[threadIdx.x + off];
            smB[threadIdx.x] = make_float4(c.x + d2.x, c.y + d2.y, c.z + d2.z, c.w + d2.w);
        }
        __syncthreads();
    }
    if (threadIdx.x < 32) {
        ((float4*)psum)[blockIdx.x * 32 + threadIdx.x]  = smA[threadIdx.x];
        ((float4*)psum2)[blockIdx.x * 32 + threadIdx.x] = smB[threadIdx.x];
    }
}

// ---------- BN mid-reduce: psum[512][128] -> pmid[16][128] (coalesced float4) ----------
__global__ __launch_bounds__(256) void bn_mid(const float* __restrict__ psum, const float* __restrict__ psum2,
                                              float* __restrict__ pmid, float* __restrict__ pmid2)
{
    int c4 = threadIdx.x & 31;
    int rg = threadIdx.x >> 5;   // 0..7
    float4 s = make_float4(0.f, 0.f, 0.f, 0.f), q = make_float4(0.f, 0.f, 0.f, 0.f);
    #pragma unroll
    for (int k = 0; k < 4; ++k) {
        int r = blockIdx.x * 32 + rg + k * 8;
        float4 a = ((const float4*)psum)[r * 32 + c4];
        float4 b = ((const float4*)psum2)[r * 32 + c4];
        s.x += a.x; s.y += a.y; s.z += a.z; s.w += a.w;
        q.x += b.x; q.y += b.y; q.z += b.z; q.w += b.w;
    }
    __shared__ float4 smA[256], smB[256];
    smA[threadIdx.x] = s; smB[threadIdx.x] = q;
    __syncthreads();
    #pragma unroll
    for (int off = 128; off >= 32; off >>= 1) {
        if (threadIdx.x < off) {
            float4 a = smA[threadIdx.x], b = smA[threadIdx.x + off];
            smA[threadIdx.x] = make_float4(a.x + b.x, a.y + b.y, a.z + b.z, a.w + b.w);
            float4 c = smB[threadIdx.x], d2 = smB[threadIdx.x + off];
            smB[threadIdx.x] = make_float4(c.x + d2.x, c.y + d2.y, c.z + d2.z, c.w + d2.w);
        }
        __syncthreads();
    }
    if (threadIdx.x < 32) {
        ((float4*)pmid)[blockIdx.x * 32 + threadIdx.x]  = smA[threadIdx.x];
        ((float4*)pmid2)[blockIdx.x * 32 + threadIdx.x] = smB[threadIdx.x];
    }
}

__global__ void bn_final(const float* __restrict__ psum, const float* __restrict__ psum2,
                         const float* __restrict__ gamma, const float* __restrict__ beta,
                         float* __restrict__ scale, float* __restrict__ shift,
                         float inv_n, int nblk)
{
    int c = threadIdx.x & 127;                  // 256 threads, 2-way split over partials
    int half = threadIdx.x >> 7;
    float s = 0.f, s2 = 0.f;
    for (int b = half; b < nblk; b += 2) {
        s  += psum[b * 128 + c];
        s2 += psum2[b * 128 + c];
    }
    __shared__ float sm[256], sm2[256];
    sm[threadIdx.x] = s; sm2[threadIdx.x] = s2; __syncthreads();
    if (half == 0) {
        s  += sm[threadIdx.x + 128];
        s2 += sm2[threadIdx.x + 128];
        float mu = s * inv_n;
        float var = s2 * inv_n - mu * mu;
        float inv = rsqrtf(var + BN_EPS);
        float sc = gamma[c] * inv;
        scale[c] = sc;
        shift[c] = beta[c] - mu * sc;
    }
}

// ---------- final: out = relu(bn2(h2) + x) ----------
__global__ __launch_bounds__(256) void final_kernel(
    const float* __restrict__ h2, const float* __restrict__ x,
    const float* __restrict__ scale, const float* __restrict__ shift,
    float* __restrict__ out, int total)
{
    int i = blockIdx.x * 256 + threadIdx.x;
    if (i * 4 >= total) return;
    float4 hv = ((const float4*)h2)[i];
    float4 xv = ((const float4*)x)[i];
    int c = (i * 4) & 127;
    float4 o;
    o.x = fmaxf(hv.x * scale[c + 0] + shift[c + 0] + xv.x, 0.f);
    o.y = fmaxf(hv.y * scale[c + 1] + shift[c + 1] + xv.y, 0.f);
    o.z = fmaxf(hv.z * scale[c + 2] + shift[c + 2] + xv.z, 0.f);
    o.w = fmaxf(hv.w * scale[c + 3] + shift[c + 3] + xv.w, 0.f);
    ((float4*)out)[i] = o;
}

// ---------- launch ----------
extern "C" void kernel_launch(void* const* d_in, const int* in_sizes, int n_in,
                              void* d_out, int out_size, void* d_ws, size_t ws_size,
                              hipStream_t stream)
{
    const float* x    = (const float*)d_in[0];
    const int*   ei   = (const int*)  d_in[1];
    const float* Wl1  = (const float*)d_in[2];
    const float* Wr1  = (const float*)d_in[3];
    const float* att1 = (const float*)d_in[4];
    const float* b1   = (const float*)d_in[5];
    const float* g1   = (const float*)d_in[6];
    const float* be1  = (const float*)d_in[7];
    const float* Wl2  = (const float*)d_in[8];
    const float* Wr2  = (const float*)d_in[9];
    const float* att2 = (const float*)d_in[10];
    const float* b2   = (const float*)d_in[11];
    const float* g2   = (const float*)d_in[12];
    const float* be2  = (const float*)d_in[13];
    float* out = (float*)d_out;

    int n = in_sizes[0] / D;
    int E = in_sizes[1] / 2;
    const int* e_src = ei;
    const int* e_dst = ei + E;

    char* w = (char*)d_ws;
    auto alloc = [&](size_t bytes) -> char* {
        char* p = w;
        w += (bytes + 255) / 256 * 256;
        return p;
    };
    unsigned short* xl = (unsigned short*)alloc((size_t)n * D * 2);
    float* xr          = (float*)alloc((size_t)n * D * 4);
    float* h           = (float*)alloc((size_t)n * D * 4);
    int* row_start     = (int*)alloc((size_t)(n + 1) * 4);
    int* cnt           = (int*)alloc((size_t)n * 4);
    int* cursor        = (int*)alloc((size_t)n * 4);
    int* esrc          = (int*)alloc((size_t)(E + 16) * 4);
    int* bsum          = (int*)alloc(256 * 4);
    float* bn          = (float*)alloc(4 * 128 * 4);      // scale1, shift1, scale2, shift2
    float* psum        = (float*)alloc((size_t)BN_BLOCKS * 128 * 4);
    float* psum2       = (float*)alloc((size_t)BN_BLOCKS * 128 * 4);
    float* pmid        = (float*)alloc(16 * 128 * 4);
    float* pmid2       = (float*)alloc(16 * 128 * 4);
    unsigned short* Bp1 = (unsigned short*)alloc(32768 * 2);
    unsigned short* Bp2 = (unsigned short*)alloc(32768 * 2);

    int nb = (n + 255) / 256;
    int gemm_blocks = (((n + 31) / 32) + 3) / 4;

    zero_kernel<<<(n + 255) / 256, 256, 0, stream>>>(cnt, n, esrc + E);
    hist_kernel<<<(E + 255) / 256, 256, 0, stream>>>(e_dst, cnt, E);
    scan_block<<<nb, 256, 0, stream>>>(cnt, row_start, bsum, n);
    scan_bsum<<<1, 256, 0, stream>>>(bsum, nb);
    scan_fix<<<nb, 256, 0, stream>>>(row_start, bsum, cursor, n);
    scatter_kernel<<<(E + 255) / 256, 256, 0, stream>>>(e_src, e_dst, cursor, esrc, E);
    repack_w<<<128, 256, 0, stream>>>(Wl1, Wr1, Bp1);
    repack_w<<<128, 256, 0, stream>>>(Wl2, Wr2, Bp2);

    // layer 1
    gemm_mfma<false><<<gemm_blocks, 256, 0, stream>>>(x, Bp1, nullptr, nullptr, xl, xr, n);
    gat_kernel<<<(n + 3) / 4, 256, 0, stream>>>(xl, xr, att1, b1, row_start, esrc, h, n);
    bn_stats<<<BN_BLOCKS, 256, 0, stream>>>(h, psum, psum2, n);
    bn_mid<<<16, 256, 0, stream>>>(psum, psum2, pmid, pmid2);
    bn_final<<<1, 256, 0, stream>>>(pmid, pmid2, g1, be1, bn + 0, bn + 128, 1.0f / n, 16);

    // layer 2 (BN1+ReLU fused into GEMM A-load)
    gemm_mfma<true><<<gemm_blocks, 256, 0, stream>>>(h, Bp2, bn + 0, bn + 128, xl, xr, n);
    gat_kernel<<<(n + 3) / 4, 256, 0, stream>>>(xl, xr, att2, b2, row_start, esrc, h, n);
    bn_stats<<<BN_BLOCKS, 256, 0, stream>>>(h, psum, psum2, n);
    bn_mid<<<16, 256, 0, stream>>>(psum, psum2, pmid, pmid2);
    bn_final<<<1, 256, 0, stream>>>(pmid, pmid2, g2, be2, bn + 256, bn + 384, 1.0f / n, 16);

    final_kernel<<<((n * D / 4) + 255) / 256, 256, 0, stream>>>(h, x, bn + 256, bn + 384, out, n * D);
}